// Round 11
// baseline (144.261 us; speedup 1.0000x reference)
//
#include <hip/hip_runtime.h>
#include <hip/hip_bf16.h>
#include <stdint.h>

// Problem constants
#define B_    256
#define LS_   1024
#define LW_   1024
#define LV_   1024
#define M_    16
#define D_    5120
#define H_    2048
#define ROWS  4096   // B*M
#define N1    4096   // H (eta) + H (rho) fused
#define KW    2048   // K of the per-row (wr|wi) GEMM

typedef __hip_bfloat16 bf16;
typedef __bf16 bf16x8 __attribute__((ext_vector_type(8)));
typedef __bf16 bf16x4 __attribute__((ext_vector_type(4)));
typedef float f32x4 __attribute__((ext_vector_type(4)));

#define SB0() __builtin_amdgcn_sched_barrier(0)
#define LGKM(n) asm volatile("s_waitcnt lgkmcnt(" #n ")" ::: "memory")
#define VMC(n)  asm volatile("s_waitcnt vmcnt(" #n ")" ::: "memory")

// ---------------------------------------------------------------------------
// async global->LDS, 16B per lane (HW: wave-uniform LDS base + lane*16).
__device__ __forceinline__ void gld_lds16(const void* g, void* l) {
  auto gp = (const __attribute__((address_space(1))) uint32_t*)(uintptr_t)g;
  auto lp = (__attribute__((address_space(3))) uint32_t*)(uint32_t)(uintptr_t)l;
  __builtin_amdgcn_global_load_lds(gp, lp, 16, 0, 0);
}

// ---------------------------------------------------------------------------
// Merged preprocessing kernel (R9-proven): block-range dispatch.
__device__ __forceinline__ void transpose64_body(char* sm, const float* __restrict__ in,
                                                 bf16* __restrict__ out,
                                                 int C, int R, int r0, int c0, int t) {
  float (*tile)[65] = (float (*)[65])sm;
  const int tx = t & 15, ty = t >> 4;   // 16 x 16
#pragma unroll
  for (int i = 0; i < 4; ++i) {
    const float4 v = *(const float4*)&in[(size_t)(r0 + ty + i * 16) * C + c0 + tx * 4];
    tile[ty + i * 16][tx * 4 + 0] = v.x;
    tile[ty + i * 16][tx * 4 + 1] = v.y;
    tile[ty + i * 16][tx * 4 + 2] = v.z;
    tile[ty + i * 16][tx * 4 + 3] = v.w;
  }
  __syncthreads();
#pragma unroll
  for (int i = 0; i < 4; ++i) {
    const int n = c0 + ty + i * 16;
    bf16x4 o;
#pragma unroll
    for (int j = 0; j < 4; ++j) o[j] = (__bf16)tile[tx * 4 + j][ty + i * 16];
    *(bf16x4*)&out[(size_t)n * R + r0 + tx * 4] = o;
  }
}

__global__ void __launch_bounds__(256)
prep_kernel(const float* __restrict__ phi,
            const float* __restrict__ wMr, const float* __restrict__ wMi,
            const float* __restrict__ vM,
            const float* __restrict__ W1e, const float* __restrict__ W1r,
            const float* __restrict__ W2e,
            bf16* __restrict__ sfeat, bf16* __restrict__ Awr,
            bf16* __restrict__ W1sT, bf16* __restrict__ W1wT,
            bf16* __restrict__ W2t, float* __restrict__ hVT) {
  __shared__ __align__(16) char sm[32768];
  const int bid = blockIdx.x;
  const int t = threadIdx.x;

  if (bid < 256) {
    // ---- hv ----
    float (*vs)[16] = (float (*)[16])sm;
    float (*ws)[16] = (float (*)[16])(sm + 16384);
    const float* Wb = (bid < 128) ? W1e : W1r;
    const int nbase = (bid & 127) * 16;
    const int nout = ((bid < 128) ? 0 : 2048) + nbase;
    const int m = t & 15, nl = t >> 4;
    float acc = 0.f;
    for (int l0 = 0; l0 < 1024; l0 += 256) {
      __syncthreads();
#pragma unroll
      for (int i = 0; i < 16; ++i) {
        int e = i * 256 + t, l = e >> 4, n = e & 15;
        vs[l][n] = vM[(size_t)(l0 + l) * 16 + n];
        ws[l][n] = Wb[(size_t)(4096 + l0 + l) * 2048 + nbase + n];
      }
      __syncthreads();
#pragma unroll 8
      for (int ll = 0; ll < 256; ++ll)
        acc += vs[ll][m] * ws[ll][nl];
    }
    hVT[(size_t)(nout + nl) * 16 + m] = acc;
  } else if (bid < 4352) {
    // ---- tw1: four 2048x2048 transposes ----
    const int idx = bid - 256;
    const int z = idx >> 10, rem = idx & 1023;
    const float* src = (z == 0 || z == 2) ? W1e : W1r;
    src += (z < 2) ? 0 : (size_t)2048 * 2048;
    bf16* dst = (z < 2) ? W1sT : W1wT;
    dst += (z == 0 || z == 2) ? 0 : (size_t)2048 * 2048;
    transpose64_body(sm, src, dst, 2048, 2048, (rem >> 5) * 64, (rem & 31) * 64, t);
  } else if (bid < 4864) {
    // ---- tw2: W2e [2048,1024] -> W2t ----
    const int idx = bid - 4352;
    transpose64_body(sm, W2e, W2t, LS_, H_, (idx >> 4) * 64, (idx & 15) * 64, t);
  } else if (bid < 8960) {
    // ---- awr ----
    const int idx = bid - 4864;
    const int b = idx >> 4, l0 = (idx & 15) * 64;
    float (*tr)[17] = (float (*)[17])sm;
    float (*ti)[17] = (float (*)[17])(sm + 4352 * 4);
    const float* wrb = wMr + (size_t)b * (LW_ * M_) + (size_t)l0 * 16;
    const float* wib = wMi + (size_t)b * (LW_ * M_) + (size_t)l0 * 16;
#pragma unroll
    for (int i = 0; i < 4; ++i) {
      int e = i * 256 + t, l = e >> 4, m = e & 15;
      tr[l][m] = wrb[e];
      ti[l][m] = wib[e];
    }
    __syncthreads();
    int m = t >> 4, t4 = t & 15;
    bf16* outR = Awr + (size_t)(b * 16 + m) * KW + l0;
#pragma unroll
    for (int j = 0; j < 4; ++j) outR[t4 * 4 + j]        = __float2bfloat16(tr[t4 * 4 + j][m]);
#pragma unroll
    for (int j = 0; j < 4; ++j) outR[1024 + t4 * 4 + j] = __float2bfloat16(ti[t4 * 4 + j][m]);
  } else {
    // ---- sfeat ----
    const int i = (bid - 8960) * 256 + t;
    const int b = i >> 10, l = i & 1023;
    float p = phi[i];
    float s, c;
    sincosf(p, &s, &c);
    sfeat[b * 2048 + l]        = __float2bfloat16(0.03125f * c);
    sfeat[b * 2048 + 1024 + l] = __float2bfloat16(0.03125f * s);
  }
}

// ---------------------------------------------------------------------------
// hS2[b,c] = sum_z hSp[z][b,c] + bias[c]   (bias = b1e | b1r split at H_)
__global__ void __launch_bounds__(256)
hsum_kernel(const float* __restrict__ hSp, const float* __restrict__ b1e,
            const float* __restrict__ b1r, float* __restrict__ hS2) {
  const int i = (blockIdx.x * 256 + threadIdx.x) * 4;
  const int c = i & (N1 - 1);
  f32x4 v = *(const f32x4*)&hSp[i];
  v = v + *(const f32x4*)&hSp[(size_t)B_ * N1 + i];
  v = v + *(const f32x4*)&hSp[(size_t)2 * B_ * N1 + i];
  v = v + *(const f32x4*)&hSp[(size_t)3 * B_ * N1 + i];
  const float* bp = (c < H_) ? &b1e[c] : &b1r[c - H_];
  v = v + *(const f32x4*)bp;
  *(f32x4*)&hS2[i] = v;
}

// ---------------------------------------------------------------------------
// GEMM_W: 256x256 tile, BK=32, 8 waves, 4-deep LDS ring. R11: cluster-ahead
// read schedule — every lgkmcnt(0) waits on reads issued one 16-MFMA cluster
// earlier (zero exposed LDS wait, zero extra registers: a0-3 slots recycled).
// Epilogue (R10-proven): eta half -> relu store; rho half -> W2r partial dots.
__global__ void __launch_bounds__(512, 2)
gemm1_256_kernel(const bf16* __restrict__ A, const bf16* __restrict__ Bt,
                 const float* __restrict__ hS2, const float* __restrict__ hVT,
                 const float* __restrict__ w2r,
                 bf16* __restrict__ outH, float* __restrict__ rhoP) {
  extern __shared__ __align__(16) char smem[];
  constexpr int NT = KW / 32;   // 64 K-tiles

  const int tid  = threadIdx.x;
  const int lane = tid & 63;
  const int wave = tid >> 6;
  const int wr = wave >> 2, wc = wave & 3;   // 2 x 4 wave grid, wave-tile 128x64
  const int fr = lane & 15, fq = lane >> 4;
  const int row0 = blockIdx.y * 256, col0 = blockIdx.x * 256;

  const int slotF = (((fr & 1) << 2) | fq) ^ ((fr >> 1) & 7);
  const int aOff = (wr << 13) + ((fr >> 1) << 7) + (slotF << 4);
  const int bOff = 16384 + (wc << 12) + ((fr >> 1) << 7) + (slotF << 4);

  const int lg0 = (tid >> 3), lg1 = 64 + (tid >> 3);
  const int su0 = (tid & 7) ^ (lg0 & 7), su1 = (tid & 7) ^ (lg1 & 7);
  const int rowp0 = lg0 * 2 + (su0 >> 2), rowp1 = lg1 * 2 + (su1 >> 2);
  const int kb0 = (su0 & 3) << 4, kb1 = (su1 & 3) << 4;
  const char* pA0 = (const char*)A  + (size_t)(row0 + rowp0) * (KW * 2) + kb0;
  const char* pA1 = (const char*)A  + (size_t)(row0 + rowp1) * (KW * 2) + kb1;
  const char* pB0 = (const char*)Bt + (size_t)(col0 + rowp0) * (KW * 2) + kb0;
  const char* pB1 = (const char*)Bt + (size_t)(col0 + rowp1) * (KW * 2) + kb1;

  auto stageTile = [&](int T) {   // 4 gld per wave
    char* dst = smem + (size_t)(T & 3) * 32768;
    const size_t ko = (size_t)T * 64;
    gld_lds16(pA0 + ko, dst + 0     + tid * 16);
    gld_lds16(pA1 + ko, dst + 8192  + tid * 16);
    gld_lds16(pB0 + ko, dst + 16384 + tid * 16);
    gld_lds16(pB1 + ko, dst + 24576 + tid * 16);
  };

  f32x4 acc[8][4] = {};
  bf16x8 a[8];          // a[0..3]: current low quad / next-tile prefetch target
  bf16x8 bA[4], bB[4];

  // prologue: stage 0,1,2; VMC(4) -> bufs 0,1 landed; pre-read a0-3(0)+b(0)
  stageTile(0); stageTile(1); stageTile(2);
  VMC(4);
  __builtin_amdgcn_s_barrier();
  {
    const char* aP0 = smem + aOff;
    const char* bP0 = smem + bOff;
#pragma unroll
    for (int m = 0; m < 4; ++m) a[m] = *(const bf16x8*)(aP0 + m * 1024);
#pragma unroll
    for (int n = 0; n < 4; ++n) bA[n] = *(const bf16x8*)(bP0 + n * 1024);
  }
  SB0();

  auto doIter = [&](int T, bf16x8 (&bCur)[4], bf16x8 (&bNxt)[4]) {
    const char* aP  = smem + (size_t)(T & 3) * 32768 + aOff;
    const char* aPn = smem + (size_t)((T + 1) & 3) * 32768 + aOff;
    const char* bPn = smem + (size_t)((T + 1) & 3) * 32768 + bOff;
    const bool rb = (T + 1 < NT);
    const bool pf = (T + 3 < NT);

    // ---- C0: wait a0-3(T)+b(T) (issued 1 cluster ago); issue a4-7(T); MFMA
    LGKM(0);
    SB0();
#pragma unroll
    for (int m = 4; m < 8; ++m) a[m] = *(const bf16x8*)(aP + m * 1024);
    SB0();
    __builtin_amdgcn_s_setprio(1);
#pragma unroll
    for (int m = 0; m < 4; ++m)
#pragma unroll
      for (int n = 0; n < 4; ++n)
        acc[m][n] = __builtin_amdgcn_mfma_f32_16x16x32_bf16(a[m], bCur[n], acc[m][n], 0, 0, 0);
    __builtin_amdgcn_s_setprio(0);
    SB0();

    // ---- C1: stage T+3; wait a4-7(T); issue a0-3(T+1)+b(T+1); MFMA
    if (pf) stageTile(T + 3);
    LGKM(0);
    SB0();
    if (rb) {
#pragma unroll
      for (int m = 0; m < 4; ++m) a[m] = *(const bf16x8*)(aPn + m * 1024);
#pragma unroll
      for (int n = 0; n < 4; ++n) bNxt[n] = *(const bf16x8*)(bPn + n * 1024);
    }
    SB0();
    __builtin_amdgcn_s_setprio(1);
#pragma unroll
    for (int m = 4; m < 8; ++m)
#pragma unroll
      for (int n = 0; n < 4; ++n)
        acc[m][n] = __builtin_amdgcn_mfma_f32_16x16x32_bf16(a[m], bCur[n], acc[m][n], 0, 0, 0);
    __builtin_amdgcn_s_setprio(0);
    SB0();
    if (pf) { VMC(4); }
    else    { VMC(0); }
    __builtin_amdgcn_s_barrier();
  };

  for (int t = 0; t < NT; t += 2) {
    doIter(t,     bA, bB);
    doIter(t + 1, bB, bA);
  }

  if (col0 < H_) {
    // eta half: h = relu(acc + hS2 + hVT)
#pragma unroll
    for (int n = 0; n < 4; ++n) {
      const int c = col0 + wc * 64 + n * 16 + fr;
      const f32x4 hv = *(const f32x4*)&hVT[(size_t)c * 16 + fq * 4];
#pragma unroll
      for (int m = 0; m < 8; ++m) {
        const int rbase = row0 + wr * 128 + m * 16;
        const float hs = hS2[(size_t)(rbase >> 4) * N1 + c];
#pragma unroll
        for (int j = 0; j < 4; ++j) {
          const int r = rbase + fq * 4 + j;
          float v = acc[m][n][j] + hs + hv[j];
          outH[(size_t)r * N1 + c] = __float2bfloat16(v > 0.f ? v : 0.f);
        }
      }
    }
  } else {
    // rho half: partial dot with W2r; no h store
    const int cb = (col0 >> 8) - 8;   // 0..7
    float* rhoT = (float*)smem;       // ring is dead
    f32x4 hv4[4];
    float w2[4];
#pragma unroll
    for (int n = 0; n < 4; ++n) {
      const int c = col0 + wc * 64 + n * 16 + fr;
      hv4[n] = *(const f32x4*)&hVT[(size_t)c * 16 + fq * 4];
      w2[n] = w2r[c - H_];
    }
#pragma unroll
    for (int m = 0; m < 8; ++m) {
      const int rbase = row0 + wr * 128 + m * 16;
      const float* hrow = &hS2[(size_t)(rbase >> 4) * N1];
      f32x4 rsv = {0.f, 0.f, 0.f, 0.f};
#pragma unroll
      for (int n = 0; n < 4; ++n) {
        const int c = col0 + wc * 64 + n * 16 + fr;
        const float hs = hrow[c];
#pragma unroll
        for (int j = 0; j < 4; ++j) {
          float v = acc[m][n][j] + hs + hv4[n][j];
          v = v > 0.f ? v : 0.f;
          rsv[j] += v * w2[n];
        }
      }
#pragma unroll
      for (int j = 0; j < 4; ++j) {
        rsv[j] += __shfl_xor(rsv[j], 1);
        rsv[j] += __shfl_xor(rsv[j], 2);
        rsv[j] += __shfl_xor(rsv[j], 4);
        rsv[j] += __shfl_xor(rsv[j], 8);
      }
      if (fr == 0)
        *(f32x4*)&rhoT[((wr * 4 + wc) << 7) + m * 16 + fq * 4] = rsv;
    }
    __syncthreads();
    if (tid < 256) {
      const int wrr = tid >> 7, lr = tid & 127;
      const float* rt = &rhoT[(wrr * 4) << 7];
      const float s = rt[lr] + rt[128 + lr] + rt[256 + lr] + rt[384 + lr];
      rhoP[(size_t)(row0 + wrr * 128 + lr) * 8 + cb] = s;
    }
  }
}

// ---------------------------------------------------------------------------
// gemm128_pipe: 128x128 tile, BK=32, 4 waves (2x2), 4-deep LDS ring. R11:
// tile-ahead read schedule (aCur/aNxt + bCur/bNxt double sets) — lgkmcnt(0)
// waits on reads issued a full tile earlier.
// EPI 0 (GEMM2): rhoP reduce prologue; out1 scatter; out0 = phi - eta.
// EPI 1 (GEMM_S split-K): blockIdx.z selects K-slice of 512 + partial buffer.
template <int EPI, int NT>
__global__ void __launch_bounds__(256, 2)
gemm128_pipe_kernel(const bf16* __restrict__ A, int lda,
                    const bf16* __restrict__ Bt, int ldb,
                    const float* __restrict__ bias0,
                    const float* __restrict__ rhoP, const float* __restrict__ b2r,
                    const float* __restrict__ phi,
                    float* __restrict__ outS, float* __restrict__ out0) {
  extern __shared__ __align__(16) char smem[];

  if (EPI == 1) {
    const int z = blockIdx.z;
    A    += (size_t)z * 512;
    Bt   += (size_t)z * 512;
    outS += (size_t)z * ((size_t)B_ * N1);
  }

  const int tid  = threadIdx.x;
  const int lane = tid & 63;
  const int wave = tid >> 6;                 // 0..3
  const int wr = wave >> 1, wc = wave & 1;   // 2x2 wave grid
  const int fr = lane & 15, fq = lane >> 4;
  const int row0 = blockIdx.y * 128, col0 = blockIdx.x * 128;

  // rho prologue (EPI 0)
  if (EPI == 0) {
    if (tid < 128) {
      const float* pp = &rhoP[(size_t)(row0 + tid) * 8];
      const f32x4 p0 = *(const f32x4*)pp;
      const f32x4 p1 = *(const f32x4*)(pp + 4);
      const float s = p0[0] + p0[1] + p0[2] + p0[3] +
                      p1[0] + p1[1] + p1[2] + p1[3] + b2r[0];
      ((float*)(smem + 65536))[tid] = s;
    }
    LGKM(0);
    SB0();
  }

  const int slotF = (((fr & 1) << 2) | fq) ^ ((fr >> 1) & 7);
  const int aOff = (wr << 12) + ((fr >> 1) << 7) + (slotF << 4);
  const int bOff = 8192 + (wc << 12) + ((fr >> 1) << 7) + (slotF << 4);

  const int lgl = tid >> 3;
  const int su  = (tid & 7) ^ (lgl & 7);
  const int rp0 = lgl * 2 + (su >> 2);
  const int rp1 = (32 + lgl) * 2 + (su >> 2);
  const int kb  = (su & 3) << 4;
  const char* pA0 = (const char*)A  + (size_t)(row0 + rp0) * ((size_t)lda * 2) + kb;
  const char* pA1 = (const char*)A  + (size_t)(row0 + rp1) * ((size_t)lda * 2) + kb;
  const char* pB0 = (const char*)Bt + (size_t)(col0 + rp0) * ((size_t)ldb * 2) + kb;
  const char* pB1 = (const char*)Bt + (size_t)(col0 + rp1) * ((size_t)ldb * 2) + kb;

  auto stageTile = [&](int T) {   // 4 gld per wave
    char* dst = smem + (size_t)(T & 3) * 16384;
    const size_t ko = (size_t)T * 64;
    gld_lds16(pA0 + ko, dst + 0     + tid * 16);
    gld_lds16(pA1 + ko, dst + 4096  + tid * 16);
    gld_lds16(pB0 + ko, dst + 8192  + tid * 16);
    gld_lds16(pB1 + ko, dst + 12288 + tid * 16);
  };

  f32x4 acc[4][4] = {};
  bf16x8 aA[4], aB[4], bA[4], bB[4];

  stageTile(0); stageTile(1); stageTile(2);
  VMC(4);
  __builtin_amdgcn_s_barrier();
  {
    const char* aP0 = smem + aOff;
    const char* bP0 = smem + bOff;
#pragma unroll
    for (int m = 0; m < 4; ++m) aA[m] = *(const bf16x8*)(aP0 + m * 1024);
#pragma unroll
    for (int n = 0; n < 4; ++n) bA[n] = *(const bf16x8*)(bP0 + n * 1024);
  }
  SB0();

  auto doIter = [&](int T, bf16x8 (&aCur)[4], bf16x8 (&bCur)[4],
                    bf16x8 (&aNxt)[4], bf16x8 (&bNxt)[4]) {
    const char* aPn = smem + (size_t)((T + 1) & 3) * 16384 + aOff;
    const char* bPn = smem + (size_t)((T + 1) & 3) * 16384 + bOff;
    const bool rb = (T + 1 < NT);
    const bool pf = (T + 3 < NT);

    if (pf) stageTile(T + 3);
    LGKM(0);                 // aCur,bCur ready (issued during tile T-1)
    SB0();
    if (rb) {
#pragma unroll
      for (int m = 0; m < 4; ++m) aNxt[m] = *(const bf16x8*)(aPn + m * 1024);
#pragma unroll
      for (int n = 0; n < 4; ++n) bNxt[n] = *(const bf16x8*)(bPn + n * 1024);
    }
    SB0();
    __builtin_amdgcn_s_setprio(1);
#pragma unroll
    for (int m = 0; m < 4; ++m)
#pragma unroll
      for (int n = 0; n < 4; ++n)
        acc[m][n] = __builtin_amdgcn_mfma_f32_16x16x32_bf16(aCur[m], bCur[n], acc[m][n], 0, 0, 0);
    __builtin_amdgcn_s_setprio(0);
    SB0();
    if (pf) { VMC(4); }
    else    { VMC(0); }
    __builtin_amdgcn_s_barrier();
  };

  for (int t = 0; t < NT; t += 2) {
    doIter(t,     aA, bA, aB, bB);
    doIter(t + 1, aB, bB, aA, bA);
  }

  if (EPI == 0) {
    const float* rhoL = (const float*)(smem + 65536);
#pragma unroll
    for (int m = 0; m < 4; ++m) {
      const int bg = (row0 >> 4) + wr * 4 + m;                 // batch index
      const f32x4 rv = *(const f32x4*)&rhoL[wr * 64 + m * 16 + fq * 4];
#pragma unroll
      for (int n = 0; n < 4; ++n) {
        const int c = col0 + wc * 64 + n * 16 + fr;
        const float bias = bias0[c];
        float part = 0.f;
#pragma unroll
        for (int j = 0; j < 4; ++j) {
          float v = acc[m][n][j] + bias;
          outS[(size_t)bg * (LS_ * M_) + (size_t)c * M_ + (fq * 4 + j)] = v;
          part += rv[j] * v;
        }
        part += __shfl_xor(part, 16);
        part += __shfl_xor(part, 32);
        if (fq == 0)
          out0[(size_t)bg * LS_ + c] = phi[(size_t)bg * LS_ + c] - part;
      }
    }
  } else {
#pragma unroll
    for (int m = 0; m < 4; ++m) {
#pragma unroll
      for (int n = 0; n < 4; ++n) {
        const int c = col0 + wc * 64 + n * 16 + fr;
#pragma unroll
        for (int j = 0; j < 4; ++j) {
          const int r = row0 + wr * 64 + m * 16 + fq * 4 + j;
          outS[(size_t)r * N1 + c] = acc[m][n][j];
        }
      }
    }
  }
}

// ---------------------------------------------------------------------------
extern "C" void kernel_launch(void* const* d_in, const int* in_sizes, int n_in,
                              void* d_out, int out_size, void* d_ws, size_t ws_size,
                              hipStream_t stream) {
  const float* phi = (const float*)d_in[0];
  const float* wMr = (const float*)d_in[1];
  const float* wMi = (const float*)d_in[2];
  const float* vM  = (const float*)d_in[3];
  const float* W1e = (const float*)d_in[4];
  const float* b1e = (const float*)d_in[5];
  const float* W2e = (const float*)d_in[6];
  const float* b2e = (const float*)d_in[7];
  const float* W1r = (const float*)d_in[8];
  const float* b1r = (const float*)d_in[9];
  const float* W2r = (const float*)d_in[10];
  const float* b2r = (const float*)d_in[11];

  float* out0 = (float*)d_out;            // phi_optimal [B, LS]
  float* out1 = out0 + (size_t)B_ * LS_;  // eta_M^T     [B, LS, M]

  bf16* Awr   = (bf16*)d_ws;                         // [4096, 2048]
  bf16* W1sT  = Awr  + (size_t)ROWS * KW;            // [4096, 2048]
  bf16* W1wT  = W1sT + (size_t)N1 * KW;              // [4096, 2048]
  bf16* h     = W1wT + (size_t)N1 * KW;              // [4096, 4096] (eta half used)
  bf16* W2t   = h + (size_t)ROWS * N1;               // [1024, 2048]
  bf16* sfeat = W2t + (size_t)LS_ * H_;              // [256, 2048]
  float* hSp  = (float*)(sfeat + (size_t)B_ * 2048); // 4 x [256, 4096] partials
  float* hS2  = hSp + (size_t)4 * B_ * N1;           // [256, 4096] summed + bias
  float* hVT  = hS2 + (size_t)B_ * N1;               // [4096, 16]
  float* rhoP = hVT + (size_t)N1 * 16;               // [4096, 8] rho partials

  (void)hipFuncSetAttribute(reinterpret_cast<const void*>(gemm1_256_kernel),
                            hipFuncAttributeMaxDynamicSharedMemorySize, 131072);
  (void)hipFuncSetAttribute(reinterpret_cast<const void*>(gemm128_pipe_kernel<0, 64>),
                            hipFuncAttributeMaxDynamicSharedMemorySize, 66048);
  (void)hipFuncSetAttribute(reinterpret_cast<const void*>(gemm128_pipe_kernel<1, 16>),
                            hipFuncAttributeMaxDynamicSharedMemorySize, 65536);

  // merged preprocessing: hv | 4x W1-transpose | W2-transpose | awr | sfeat
  prep_kernel<<<9984, 256, 0, stream>>>(phi, wMr, wMi, vM, W1e, W1r, W2e,
                                        sfeat, Awr, W1sT, W1wT, W2t, hVT);

  // GEMM_S split-K x4: hSp[z] = sfeat @ W1sT[:, z*512:(z+1)*512]^T
  gemm128_pipe_kernel<1, 16><<<dim3(N1 / 128, B_ / 128, 4), 256, 65536, stream>>>(
      sfeat, 2048, W1sT, KW, nullptr, nullptr, nullptr, nullptr, hSp, nullptr);

  // hS2 = sum4(hSp) + bias
  hsum_kernel<<<(B_ * N1 / 4) / 256, 256, 0, stream>>>(hSp, b1e, b1r, hS2);

  // GEMM_W: h(eta half) = relu(Awr@W1wT^T + hS2 + hVT); rho partials
  gemm1_256_kernel<<<dim3(N1 / 256, ROWS / 256), 512, 131072, stream>>>(
      Awr, W1wT, hS2, hVT, W2r, h, rhoP);

  // GEMM2: rho reduce (prologue) + out1 scatter + out0 = phi - eta
  gemm128_pipe_kernel<0, 64><<<dim3(LS_ / 128, ROWS / 128), 256, 66048, stream>>>(
      h, N1, W2t, H_, b2e, rhoP, b2r, phi, out1, out0);
}

// Round 12
// 140.967 us; speedup vs baseline: 1.0234x; 1.0234x over previous
//
#include <hip/hip_runtime.h>
#include <hip/hip_bf16.h>
#include <stdint.h>

// Problem constants
#define B_    256
#define LS_   1024
#define LW_   1024
#define LV_   1024
#define M_    16
#define D_    5120
#define H_    2048
#define ROWS  4096   // B*M
#define N1    4096   // H (eta) + H (rho) fused
#define KW    2048   // K of the per-row (wr|wi) GEMM

typedef __hip_bfloat16 bf16;
typedef __bf16 bf16x8 __attribute__((ext_vector_type(8)));
typedef __bf16 bf16x4 __attribute__((ext_vector_type(4)));
typedef float f32x4 __attribute__((ext_vector_type(4)));

#define SB0() __builtin_amdgcn_sched_barrier(0)
#define LGKM(n) asm volatile("s_waitcnt lgkmcnt(" #n ")" ::: "memory")
#define VMC(n)  asm volatile("s_waitcnt vmcnt(" #n ")" ::: "memory")
#define BARv()  __builtin_amdgcn_s_barrier()

// ---------------------------------------------------------------------------
// async global->LDS, 16B per lane (HW: wave-uniform LDS base + lane*16).
__device__ __forceinline__ void gld_lds16(const void* g, void* l) {
  auto gp = (const __attribute__((address_space(1))) uint32_t*)(uintptr_t)g;
  auto lp = (__attribute__((address_space(3))) uint32_t*)(uint32_t)(uintptr_t)l;
  __builtin_amdgcn_global_load_lds(gp, lp, 16, 0, 0);
}

// ---------------------------------------------------------------------------
// Merged preprocessing kernel (R9-proven): block-range dispatch.
__device__ __forceinline__ void transpose64_body(char* sm, const float* __restrict__ in,
                                                 bf16* __restrict__ out,
                                                 int C, int R, int r0, int c0, int t) {
  float (*tile)[65] = (float (*)[65])sm;
  const int tx = t & 15, ty = t >> 4;   // 16 x 16
#pragma unroll
  for (int i = 0; i < 4; ++i) {
    const float4 v = *(const float4*)&in[(size_t)(r0 + ty + i * 16) * C + c0 + tx * 4];
    tile[ty + i * 16][tx * 4 + 0] = v.x;
    tile[ty + i * 16][tx * 4 + 1] = v.y;
    tile[ty + i * 16][tx * 4 + 2] = v.z;
    tile[ty + i * 16][tx * 4 + 3] = v.w;
  }
  __syncthreads();
#pragma unroll
  for (int i = 0; i < 4; ++i) {
    const int n = c0 + ty + i * 16;
    bf16x4 o;
#pragma unroll
    for (int j = 0; j < 4; ++j) o[j] = (__bf16)tile[tx * 4 + j][ty + i * 16];
    *(bf16x4*)&out[(size_t)n * R + r0 + tx * 4] = o;
  }
}

__global__ void __launch_bounds__(256)
prep_kernel(const float* __restrict__ phi,
            const float* __restrict__ wMr, const float* __restrict__ wMi,
            const float* __restrict__ vM,
            const float* __restrict__ W1e, const float* __restrict__ W1r,
            const float* __restrict__ W2e,
            bf16* __restrict__ sfeat, bf16* __restrict__ Awr,
            bf16* __restrict__ W1sT, bf16* __restrict__ W1wT,
            bf16* __restrict__ W2t, float* __restrict__ hVT) {
  __shared__ __align__(16) char sm[32768];
  const int bid = blockIdx.x;
  const int t = threadIdx.x;

  if (bid < 256) {
    // ---- hv ----
    float (*vs)[16] = (float (*)[16])sm;
    float (*ws)[16] = (float (*)[16])(sm + 16384);
    const float* Wb = (bid < 128) ? W1e : W1r;
    const int nbase = (bid & 127) * 16;
    const int nout = ((bid < 128) ? 0 : 2048) + nbase;
    const int m = t & 15, nl = t >> 4;
    float acc = 0.f;
    for (int l0 = 0; l0 < 1024; l0 += 256) {
      __syncthreads();
#pragma unroll
      for (int i = 0; i < 16; ++i) {
        int e = i * 256 + t, l = e >> 4, n = e & 15;
        vs[l][n] = vM[(size_t)(l0 + l) * 16 + n];
        ws[l][n] = Wb[(size_t)(4096 + l0 + l) * 2048 + nbase + n];
      }
      __syncthreads();
#pragma unroll 8
      for (int ll = 0; ll < 256; ++ll)
        acc += vs[ll][m] * ws[ll][nl];
    }
    hVT[(size_t)(nout + nl) * 16 + m] = acc;
  } else if (bid < 4352) {
    // ---- tw1: four 2048x2048 transposes ----
    const int idx = bid - 256;
    const int z = idx >> 10, rem = idx & 1023;
    const float* src = (z == 0 || z == 2) ? W1e : W1r;
    src += (z < 2) ? 0 : (size_t)2048 * 2048;
    bf16* dst = (z < 2) ? W1sT : W1wT;
    dst += (z == 0 || z == 2) ? 0 : (size_t)2048 * 2048;
    transpose64_body(sm, src, dst, 2048, 2048, (rem >> 5) * 64, (rem & 31) * 64, t);
  } else if (bid < 4864) {
    // ---- tw2: W2e [2048,1024] -> W2t ----
    const int idx = bid - 4352;
    transpose64_body(sm, W2e, W2t, LS_, H_, (idx >> 4) * 64, (idx & 15) * 64, t);
  } else if (bid < 8960) {
    // ---- awr ----
    const int idx = bid - 4864;
    const int b = idx >> 4, l0 = (idx & 15) * 64;
    float (*tr)[17] = (float (*)[17])sm;
    float (*ti)[17] = (float (*)[17])(sm + 4352 * 4);
    const float* wrb = wMr + (size_t)b * (LW_ * M_) + (size_t)l0 * 16;
    const float* wib = wMi + (size_t)b * (LW_ * M_) + (size_t)l0 * 16;
#pragma unroll
    for (int i = 0; i < 4; ++i) {
      int e = i * 256 + t, l = e >> 4, m = e & 15;
      tr[l][m] = wrb[e];
      ti[l][m] = wib[e];
    }
    __syncthreads();
    int m = t >> 4, t4 = t & 15;
    bf16* outR = Awr + (size_t)(b * 16 + m) * KW + l0;
#pragma unroll
    for (int j = 0; j < 4; ++j) outR[t4 * 4 + j]        = __float2bfloat16(tr[t4 * 4 + j][m]);
#pragma unroll
    for (int j = 0; j < 4; ++j) outR[1024 + t4 * 4 + j] = __float2bfloat16(ti[t4 * 4 + j][m]);
  } else {
    // ---- sfeat ----
    const int i = (bid - 8960) * 256 + t;
    const int b = i >> 10, l = i & 1023;
    float p = phi[i];
    float s, c;
    sincosf(p, &s, &c);
    sfeat[b * 2048 + l]        = __float2bfloat16(0.03125f * c);
    sfeat[b * 2048 + 1024 + l] = __float2bfloat16(0.03125f * s);
  }
}

// ---------------------------------------------------------------------------
// hS2[b,c] = sum_z hSp[z][b,c] + bias[c]   (bias = b1e | b1r split at H_)
__global__ void __launch_bounds__(256)
hsum_kernel(const float* __restrict__ hSp, const float* __restrict__ b1e,
            const float* __restrict__ b1r, float* __restrict__ hS2) {
  const int i = (blockIdx.x * 256 + threadIdx.x) * 4;
  const int c = i & (N1 - 1);
  f32x4 v = *(const f32x4*)&hSp[i];
  v = v + *(const f32x4*)&hSp[(size_t)B_ * N1 + i];
  v = v + *(const f32x4*)&hSp[(size_t)2 * B_ * N1 + i];
  v = v + *(const f32x4*)&hSp[(size_t)3 * B_ * N1 + i];
  const float* bp = (c < H_) ? &b1e[c] : &b1r[c - H_];
  v = v + *(const f32x4*)bp;
  *(f32x4*)&hS2[i] = v;
}

// ---------------------------------------------------------------------------
// GEMM_W: 256x256 tile, BK=64, 8 waves (2x4), m201 8-phase schedule.
// Even K-tiles live in buf0, odd in buf1 (fixed). Per K-tile 4 phases =
// quadrants (m-half x k-step), reads 8/4/8/4 per wave; 1 staged half-tile
// (2 gld) per phase; VMC(2) at P4/P8 only.
// Region-free derivation (buf0; buf1 mirrors at P5-P8):
//   B(buf0) last read P3 (b ks1)  -> stage B halves at P4,P5
//   A(buf0) last read P4 (a ks1)  -> stage A halves at P6,P7
//   B(buf1) last read P7          -> stage B-lo(next odd) at P8, B-hi at P1'
//   A(buf1) last read P8          -> stage A halves at P2',P3'
// vmcnt: before P1 reads buf0(2t+2): newest-2 = P8's stage -> VMC(2)@P8.
//        before P5 reads buf1(2t+1): newest-2 = P4's stage -> VMC(2)@P4.
// Epilogue (R10-proven): eta half -> relu store; rho half -> W2r partial dots.
__global__ void __launch_bounds__(512, 2)
gemm1_256_kernel(const bf16* __restrict__ A, const bf16* __restrict__ Bt,
                 const float* __restrict__ hS2, const float* __restrict__ hVT,
                 const float* __restrict__ w2r,
                 bf16* __restrict__ outH, float* __restrict__ rhoP) {
  extern __shared__ __align__(16) char smem[];
  constexpr int NKT = KW / 64;   // 32 K-tiles of 64
  constexpr int NI  = NKT / 2;   // 16 iterations (2 tiles each)

  const int tid  = threadIdx.x;
  const int lane = tid & 63;
  const int wave = tid >> 6;
  const int wr = wave >> 2, wc = wave & 3;   // 2 x 4 wave grid, wave-tile 128x64
  const int fr = lane & 15, fq = lane >> 4;
  const int row0 = blockIdx.y * 256, col0 = blockIdx.x * 256;

  // fragment read statics: row = (wr*128 | wc*64) + tile*16 + fr; 128B/row;
  // slot (16B) for k-step ks, octet fq stored at (ks*4+fq)^(fr&7).
  const int xr  = fr & 7;
  const int sK0 = ((fq ^ xr) << 4);
  const int sK1 = (((4 + fq) ^ xr) << 4);
  const int aRowB = (wr * 128 + fr) << 7;
  const int bRowB = 32768 + ((wc * 64 + fr) << 7);

  const char* gA = (const char*)A  + (size_t)row0 * (KW * 2);
  const char* gB = (const char*)Bt + (size_t)col0 * (KW * 2);
  char* buf0 = smem;
  char* buf1 = smem + 65536;

  // staging statics: thread t covers row = half*128 + r*64 + (t>>3), slotS=t&7;
  // LDS dest byte = opBase + half*16384 + r*8192 + t*16 (linear, wave-uniform).
  const int srow  = tid >> 3;
  const int slotU = (tid & 7) ^ (srow & 7);

  auto stageHalf = [&](const char* g, char* ldsOp, int half, int kt) {
#pragma unroll
    for (int r = 0; r < 2; ++r) {
      const int row = half * 128 + r * 64 + srow;
      gld_lds16(g + (size_t)row * (KW * 2) + (size_t)kt * 128 + slotU * 16,
                ldsOp + half * 16384 + r * 8192 + tid * 16);
    }
  };

  f32x4 acc[8][4] = {};

  auto readA4 = [&](const char* buf, int mg, int sk, bf16x8 (&a)[4]) {
    const char* p = buf + aRowB + mg * 8192 + sk;
#pragma unroll
    for (int i = 0; i < 4; ++i) a[i] = *(const bf16x8*)(p + i * 2048);
  };
  auto readB4 = [&](const char* buf, int sk, bf16x8 (&b)[4]) {
    const char* p = buf + bRowB + sk;
#pragma unroll
    for (int n = 0; n < 4; ++n) b[n] = *(const bf16x8*)(p + n * 2048);
  };
  auto mma16 = [&](int mg, bf16x8 (&a)[4], bf16x8 (&b)[4]) {
    __builtin_amdgcn_s_setprio(1);
#pragma unroll
    for (int i = 0; i < 4; ++i)
#pragma unroll
      for (int n = 0; n < 4; ++n)
        acc[mg * 4 + i][n] =
            __builtin_amdgcn_mfma_f32_16x16x32_bf16(a[i], b[n], acc[mg * 4 + i][n], 0, 0, 0);
    __builtin_amdgcn_s_setprio(0);
  };

  // prologue: tile0 -> buf0 (4 halves) + B-lo(1) -> buf1; retire tile0.
  stageHalf(gB, buf0 + 32768, 0, 0);
  stageHalf(gB, buf0 + 32768, 1, 0);
  stageHalf(gA, buf0, 0, 0);
  stageHalf(gA, buf0, 1, 0);
  stageHalf(gB, buf1 + 32768, 0, 1);
  VMC(2);
  BARv();

  for (int t = 0; t < NI; ++t) {
    const int k1 = 2 * t + 1;
    const bool pf = (t + 1 < NI);
    bf16x8 aX[4], aY[4], b0[4], b1[4];

    // P1: buf0 a(m0-3,ks0)+b(ks0); stage B-hi(k1)->buf1
    readA4(buf0, 0, sK0, aX); readB4(buf0, sK0, b0);
    stageHalf(gB, buf1 + 32768, 1, k1);
    BARv(); LGKM(0); SB0();
    mma16(0, aX, b0);
    SB0(); BARv();

    // P2: a(m4-7,ks0); stage A-lo(k1)->buf1
    readA4(buf0, 1, sK0, aY);
    stageHalf(gA, buf1, 0, k1);
    BARv(); LGKM(0); SB0();
    mma16(1, aY, b0);
    SB0(); BARv();

    // P3: a(m0-3,ks1)+b(ks1); stage A-hi(k1)->buf1
    readA4(buf0, 0, sK1, aX); readB4(buf0, sK1, b1);
    stageHalf(gA, buf1, 1, k1);
    BARv(); LGKM(0); SB0();
    mma16(0, aX, b1);
    SB0(); BARv();

    // P4: a(m4-7,ks1); stage B-lo(2t+2)->buf0; VMC(2) guards P5's buf1 reads
    readA4(buf0, 1, sK1, aY);
    if (pf) { stageHalf(gB, buf0 + 32768, 0, 2 * t + 2); VMC(2); }
    else    { VMC(0); }
    BARv(); LGKM(0); SB0();
    mma16(1, aY, b1);
    SB0(); BARv();

    // P5: buf1 a(m0-3,ks0)+b(ks0); stage B-hi(2t+2)->buf0
    readA4(buf1, 0, sK0, aX); readB4(buf1, sK0, b0);
    if (pf) stageHalf(gB, buf0 + 32768, 1, 2 * t + 2);
    BARv(); LGKM(0); SB0();
    mma16(0, aX, b0);
    SB0(); BARv();

    // P6: a(m4-7,ks0); stage A-lo(2t+2)->buf0
    readA4(buf1, 1, sK0, aY);
    if (pf) stageHalf(gA, buf0, 0, 2 * t + 2);
    BARv(); LGKM(0); SB0();
    mma16(1, aY, b0);
    SB0(); BARv();

    // P7: a(m0-3,ks1)+b(ks1); stage A-hi(2t+2)->buf0
    readA4(buf1, 0, sK1, aX); readB4(buf1, sK1, b1);
    if (pf) stageHalf(gA, buf0, 1, 2 * t + 2);
    BARv(); LGKM(0); SB0();
    mma16(0, aX, b1);
    SB0(); BARv();

    // P8: a(m4-7,ks1); stage B-lo(2t+3)->buf1; VMC(2) guards next P1
    readA4(buf1, 1, sK1, aY);
    if (pf) { stageHalf(gB, buf1 + 32768, 0, 2 * t + 3); VMC(2); }
    else    { VMC(0); }
    BARv(); LGKM(0); SB0();
    mma16(1, aY, b1);
    SB0(); BARv();
  }

  if (col0 < H_) {
    // eta half: h = relu(acc + hS2 + hVT)
#pragma unroll
    for (int n = 0; n < 4; ++n) {
      const int c = col0 + wc * 64 + n * 16 + fr;
      const f32x4 hv = *(const f32x4*)&hVT[(size_t)c * 16 + fq * 4];
#pragma unroll
      for (int m = 0; m < 8; ++m) {
        const int rbase = row0 + wr * 128 + m * 16;
        const float hs = hS2[(size_t)(rbase >> 4) * N1 + c];
#pragma unroll
        for (int j = 0; j < 4; ++j) {
          const int r = rbase + fq * 4 + j;
          float v = acc[m][n][j] + hs + hv[j];
          outH[(size_t)r * N1 + c] = __float2bfloat16(v > 0.f ? v : 0.f);
        }
      }
    }
  } else {
    // rho half: partial dot with W2r; no h store
    const int cb = (col0 >> 8) - 8;   // 0..7
    float* rhoT = (float*)smem;       // ring is dead
    f32x4 hv4[4];
    float w2[4];
#pragma unroll
    for (int n = 0; n < 4; ++n) {
      const int c = col0 + wc * 64 + n * 16 + fr;
      hv4[n] = *(const f32x4*)&hVT[(size_t)c * 16 + fq * 4];
      w2[n] = w2r[c - H_];
    }
#pragma unroll
    for (int m = 0; m < 8; ++m) {
      const int rbase = row0 + wr * 128 + m * 16;
      const float* hrow = &hS2[(size_t)(rbase >> 4) * N1];
      f32x4 rsv = {0.f, 0.f, 0.f, 0.f};
#pragma unroll
      for (int n = 0; n < 4; ++n) {
        const int c = col0 + wc * 64 + n * 16 + fr;
        const float hs = hrow[c];
#pragma unroll
        for (int j = 0; j < 4; ++j) {
          float v = acc[m][n][j] + hs + hv4[n][j];
          v = v > 0.f ? v : 0.f;
          rsv[j] += v * w2[n];
        }
      }
#pragma unroll
      for (int j = 0; j < 4; ++j) {
        rsv[j] += __shfl_xor(rsv[j], 1);
        rsv[j] += __shfl_xor(rsv[j], 2);
        rsv[j] += __shfl_xor(rsv[j], 4);
        rsv[j] += __shfl_xor(rsv[j], 8);
      }
      if (fr == 0)
        *(f32x4*)&rhoT[((wr * 4 + wc) << 7) + m * 16 + fq * 4] = rsv;
    }
    __syncthreads();
    if (tid < 256) {
      const int wrr = tid >> 7, lr = tid & 127;
      const float* rt = &rhoT[(wrr * 4) << 7];
      const float s = rt[lr] + rt[128 + lr] + rt[256 + lr] + rt[384 + lr];
      rhoP[(size_t)(row0 + wrr * 128 + lr) * 8 + cb] = s;
    }
  }
}

// ---------------------------------------------------------------------------
// gemm128_pipe (R11-proven): 128x128 tile, BK=32, 4 waves, 4-deep LDS ring,
// tile-ahead reads. EPI 0 (GEMM2): rhoP reduce prologue; out1 scatter;
// out0 = phi - eta. EPI 1 (GEMM_S split-K): blockIdx.z selects K-slice.
template <int EPI, int NT>
__global__ void __launch_bounds__(256, 2)
gemm128_pipe_kernel(const bf16* __restrict__ A, int lda,
                    const bf16* __restrict__ Bt, int ldb,
                    const float* __restrict__ bias0,
                    const float* __restrict__ rhoP, const float* __restrict__ b2r,
                    const float* __restrict__ phi,
                    float* __restrict__ outS, float* __restrict__ out0) {
  extern __shared__ __align__(16) char smem[];

  if (EPI == 1) {
    const int z = blockIdx.z;
    A    += (size_t)z * 512;
    Bt   += (size_t)z * 512;
    outS += (size_t)z * ((size_t)B_ * N1);
  }

  const int tid  = threadIdx.x;
  const int lane = tid & 63;
  const int wave = tid >> 6;                 // 0..3
  const int wr = wave >> 1, wc = wave & 1;   // 2x2 wave grid
  const int fr = lane & 15, fq = lane >> 4;
  const int row0 = blockIdx.y * 128, col0 = blockIdx.x * 128;

  // rho prologue (EPI 0)
  if (EPI == 0) {
    if (tid < 128) {
      const float* pp = &rhoP[(size_t)(row0 + tid) * 8];
      const f32x4 p0 = *(const f32x4*)pp;
      const f32x4 p1 = *(const f32x4*)(pp + 4);
      const float s = p0[0] + p0[1] + p0[2] + p0[3] +
                      p1[0] + p1[1] + p1[2] + p1[3] + b2r[0];
      ((float*)(smem + 65536))[tid] = s;
    }
    LGKM(0);
    SB0();
  }

  const int slotF = (((fr & 1) << 2) | fq) ^ ((fr >> 1) & 7);
  const int aOff = (wr << 12) + ((fr >> 1) << 7) + (slotF << 4);
  const int bOff = 8192 + (wc << 12) + ((fr >> 1) << 7) + (slotF << 4);

  const int lgl = tid >> 3;
  const int su  = (tid & 7) ^ (lgl & 7);
  const int rp0 = lgl * 2 + (su >> 2);
  const int rp1 = (32 + lgl) * 2 + (su >> 2);
  const int kb  = (su & 3) << 4;
  const char* pA0 = (const char*)A  + (size_t)(row0 + rp0) * ((size_t)lda * 2) + kb;
  const char* pA1 = (const char*)A  + (size_t)(row0 + rp1) * ((size_t)lda * 2) + kb;
  const char* pB0 = (const char*)Bt + (size_t)(col0 + rp0) * ((size_t)ldb * 2) + kb;
  const char* pB1 = (const char*)Bt + (size_t)(col0 + rp1) * ((size_t)ldb * 2) + kb;

  auto stageTile = [&](int T) {   // 4 gld per wave
    char* dst = smem + (size_t)(T & 3) * 16384;
    const size_t ko = (size_t)T * 64;
    gld_lds16(pA0 + ko, dst + 0     + tid * 16);
    gld_lds16(pA1 + ko, dst + 4096  + tid * 16);
    gld_lds16(pB0 + ko, dst + 8192  + tid * 16);
    gld_lds16(pB1 + ko, dst + 12288 + tid * 16);
  };

  f32x4 acc[4][4] = {};
  bf16x8 aA[4], aB[4], bA[4], bB[4];

  stageTile(0); stageTile(1); stageTile(2);
  VMC(4);
  __builtin_amdgcn_s_barrier();
  {
    const char* aP0 = smem + aOff;
    const char* bP0 = smem + bOff;
#pragma unroll
    for (int m = 0; m < 4; ++m) aA[m] = *(const bf16x8*)(aP0 + m * 1024);
#pragma unroll
    for (int n = 0; n < 4; ++n) bA[n] = *(const bf16x8*)(bP0 + n * 1024);
  }
  SB0();

  auto doIter = [&](int T, bf16x8 (&aCur)[4], bf16x8 (&bCur)[4],
                    bf16x8 (&aNxt)[4], bf16x8 (&bNxt)[4]) {
    const char* aPn = smem + (size_t)((T + 1) & 3) * 16384 + aOff;
    const char* bPn = smem + (size_t)((T + 1) & 3) * 16384 + bOff;
    const bool rb = (T + 1 < NT);
    const bool pf = (T + 3 < NT);

    if (pf) stageTile(T + 3);
    LGKM(0);                 // aCur,bCur ready (issued during tile T-1)
    SB0();
    if (rb) {
#pragma unroll
      for (int m = 0; m < 4; ++m) aNxt[m] = *(const bf16x8*)(aPn + m * 1024);
#pragma unroll
      for (int n = 0; n < 4; ++n) bNxt[n] = *(const bf16x8*)(bPn + n * 1024);
    }
    SB0();
    __builtin_amdgcn_s_setprio(1);
#pragma unroll
    for (int m = 0; m < 4; ++m)
#pragma unroll
      for (int n = 0; n < 4; ++n)
        acc[m][n] = __builtin_amdgcn_mfma_f32_16x16x32_bf16(aCur[m], bCur[n], acc[m][n], 0, 0, 0);
    __builtin_amdgcn_s_setprio(0);
    SB0();
    if (pf) { VMC(4); }
    else    { VMC(0); }
    __builtin_amdgcn_s_barrier();
  };

  for (int t = 0; t < NT; t += 2) {
    doIter(t,     aA, bA, aB, bB);
    doIter(t + 1, aB, bB, aA, bA);
  }

  if (EPI == 0) {
    const float* rhoL = (const float*)(smem + 65536);
#pragma unroll
    for (int m = 0; m < 4; ++m) {
      const int bg = (row0 >> 4) + wr * 4 + m;                 // batch index
      const f32x4 rv = *(const f32x4*)&rhoL[wr * 64 + m * 16 + fq * 4];
#pragma unroll
      for (int n = 0; n < 4; ++n) {
        const int c = col0 + wc * 64 + n * 16 + fr;
        const float bias = bias0[c];
        float part = 0.f;
#pragma unroll
        for (int j = 0; j < 4; ++j) {
          float v = acc[m][n][j] + bias;
          outS[(size_t)bg * (LS_ * M_) + (size_t)c * M_ + (fq * 4 + j)] = v;
          part += rv[j] * v;
        }
        part += __shfl_xor(part, 16);
        part += __shfl_xor(part, 32);
        if (fq == 0)
          out0[(size_t)bg * LS_ + c] = phi[(size_t)bg * LS_ + c] - part;
      }
    }
  } else {
#pragma unroll
    for (int m = 0; m < 4; ++m) {
#pragma unroll
      for (int n = 0; n < 4; ++n) {
        const int c = col0 + wc * 64 + n * 16 + fr;
#pragma unroll
        for (int j = 0; j < 4; ++j) {
          const int r = row0 + wr * 64 + m * 16 + fq * 4 + j;
          outS[(size_t)r * N1 + c] = acc[m][n][j];
        }
      }
    }
  }
}

// ---------------------------------------------------------------------------
extern "C" void kernel_launch(void* const* d_in, const int* in_sizes, int n_in,
                              void* d_out, int out_size, void* d_ws, size_t ws_size,
                              hipStream_t stream) {
  const float* phi = (const float*)d_in[0];
  const float* wMr = (const float*)d_in[1];
  const float* wMi = (const float*)d_in[2];
  const float* vM  = (const float*)d_in[3];
  const float* W1e = (const float*)d_in[4];
  const float* b1e = (const float*)d_in[5];
  const float* W2e = (const float*)d_in[6];
  const float* b2e = (const float*)d_in[7];
  const float* W1r = (const float*)d_in[8];
  const float* b1r = (const float*)d_in[9];
  const float* W2r = (const float*)d_in[10];
  const float* b2r = (const float*)d_in[11];

  float* out0 = (float*)d_out;            // phi_optimal [B, LS]
  float* out1 = out0 + (size_t)B_ * LS_;  // eta_M^T     [B, LS, M]

  bf16* Awr   = (bf16*)d_ws;                         // [4096, 2048]
  bf16* W1sT  = Awr  + (size_t)ROWS * KW;            // [4096, 2048]
  bf16* W1wT  = W1sT + (size_t)N1 * KW;              // [4096, 2048]
  bf16* h     = W1wT + (size_t)N1 * KW;              // [4096, 4096] (eta half used)
  bf16* W2t   = h + (size_t)ROWS * N1;               // [1024, 2048]
  bf16* sfeat = W2t + (size_t)LS_ * H_;              // [256, 2048]
  float* hSp  = (float*)(sfeat + (size_t)B_ * 2048); // 4 x [256, 4096] partials
  float* hS2  = hSp + (size_t)4 * B_ * N1;           // [256, 4096] summed + bias
  float* hVT  = hS2 + (size_t)B_ * N1;               // [4096, 16]
  float* rhoP = hVT + (size_t)N1 * 16;               // [4096, 8] rho partials

  (void)hipFuncSetAttribute(reinterpret_cast<const void*>(gemm1_256_kernel),
                            hipFuncAttributeMaxDynamicSharedMemorySize, 131072);
  (void)hipFuncSetAttribute(reinterpret_cast<const void*>(gemm128_pipe_kernel<0, 64>),
                            hipFuncAttributeMaxDynamicSharedMemorySize, 66048);
  (void)hipFuncSetAttribute(reinterpret_cast<const void*>(gemm128_pipe_kernel<1, 16>),
                            hipFuncAttributeMaxDynamicSharedMemorySize, 65536);

  // merged preprocessing: hv | 4x W1-transpose | W2-transpose | awr | sfeat
  prep_kernel<<<9984, 256, 0, stream>>>(phi, wMr, wMi, vM, W1e, W1r, W2e,
                                        sfeat, Awr, W1sT, W1wT, W2t, hVT);

  // GEMM_S split-K x4: hSp[z] = sfeat @ W1sT[:, z*512:(z+1)*512]^T
  gemm128_pipe_kernel<1, 16><<<dim3(N1 / 128, B_ / 128, 4), 256, 65536, stream>>>(
      sfeat, 2048, W1sT, KW, nullptr, nullptr, nullptr, nullptr, hSp, nullptr);

  // hS2 = sum4(hSp) + bias
  hsum_kernel<<<(B_ * N1 / 4) / 256, 256, 0, stream>>>(hSp, b1e, b1r, hS2);

  // GEMM_W (m201 8-phase): h(eta half) = relu(Awr@W1wT^T + hS2 + hVT); rho partials
  gemm1_256_kernel<<<dim3(N1 / 256, ROWS / 256), 512, 131072, stream>>>(
      Awr, W1wT, hS2, hVT, W2r, h, rhoP);

  // GEMM2: rho reduce (prologue) + out1 scatter + out0 = phi - eta
  gemm128_pipe_kernel<0, 64><<<dim3(LS_ / 128, ROWS / 128), 256, 66048, stream>>>(
      h, N1, W2t, H_, b2e, rhoP, b2r, phi, out1, out0);
}

// Round 13
// 139.029 us; speedup vs baseline: 1.0376x; 1.0139x over previous
//
#include <hip/hip_runtime.h>
#include <hip/hip_bf16.h>
#include <stdint.h>

// Problem constants
#define B_    256
#define LS_   1024
#define LW_   1024
#define LV_   1024
#define M_    16
#define D_    5120
#define H_    2048
#define ROWS  4096   // B*M
#define N1    4096   // H (eta) + H (rho) fused
#define KW    2048   // K of the per-row (wr|wi) GEMM

typedef __hip_bfloat16 bf16;
typedef __bf16 bf16x8 __attribute__((ext_vector_type(8)));
typedef __bf16 bf16x4 __attribute__((ext_vector_type(4)));
typedef float f32x4 __attribute__((ext_vector_type(4)));

#define SB0() __builtin_amdgcn_sched_barrier(0)
#define LGKM(n) asm volatile("s_waitcnt lgkmcnt(" #n ")" ::: "memory")
#define VMC(n)  asm volatile("s_waitcnt vmcnt(" #n ")" ::: "memory")
#define BARv()  __builtin_amdgcn_s_barrier()

// ---------------------------------------------------------------------------
// async global->LDS, 16B per lane (HW: wave-uniform LDS base + lane*16).
__device__ __forceinline__ void gld_lds16(const void* g, void* l) {
  auto gp = (const __attribute__((address_space(1))) uint32_t*)(uintptr_t)g;
  auto lp = (__attribute__((address_space(3))) uint32_t*)(uint32_t)(uintptr_t)l;
  __builtin_amdgcn_global_load_lds(gp, lp, 16, 0, 0);
}

// ---------------------------------------------------------------------------
// Merged preprocessing kernel (R9-proven): block-range dispatch.
__device__ __forceinline__ void transpose64_body(char* sm, const float* __restrict__ in,
                                                 bf16* __restrict__ out,
                                                 int C, int R, int r0, int c0, int t) {
  float (*tile)[65] = (float (*)[65])sm;
  const int tx = t & 15, ty = t >> 4;   // 16 x 16
#pragma unroll
  for (int i = 0; i < 4; ++i) {
    const float4 v = *(const float4*)&in[(size_t)(r0 + ty + i * 16) * C + c0 + tx * 4];
    tile[ty + i * 16][tx * 4 + 0] = v.x;
    tile[ty + i * 16][tx * 4 + 1] = v.y;
    tile[ty + i * 16][tx * 4 + 2] = v.z;
    tile[ty + i * 16][tx * 4 + 3] = v.w;
  }
  __syncthreads();
#pragma unroll
  for (int i = 0; i < 4; ++i) {
    const int n = c0 + ty + i * 16;
    bf16x4 o;
#pragma unroll
    for (int j = 0; j < 4; ++j) o[j] = (__bf16)tile[tx * 4 + j][ty + i * 16];
    *(bf16x4*)&out[(size_t)n * R + r0 + tx * 4] = o;
  }
}

__global__ void __launch_bounds__(256)
prep_kernel(const float* __restrict__ phi,
            const float* __restrict__ wMr, const float* __restrict__ wMi,
            const float* __restrict__ vM,
            const float* __restrict__ W1e, const float* __restrict__ W1r,
            const float* __restrict__ W2e,
            bf16* __restrict__ sfeat, bf16* __restrict__ Awr,
            bf16* __restrict__ W1sT, bf16* __restrict__ W1wT,
            bf16* __restrict__ W2t, float* __restrict__ hVT) {
  __shared__ __align__(16) char sm[32768];
  const int bid = blockIdx.x;
  const int t = threadIdx.x;

  if (bid < 256) {
    // ---- hv ----
    float (*vs)[16] = (float (*)[16])sm;
    float (*ws)[16] = (float (*)[16])(sm + 16384);
    const float* Wb = (bid < 128) ? W1e : W1r;
    const int nbase = (bid & 127) * 16;
    const int nout = ((bid < 128) ? 0 : 2048) + nbase;
    const int m = t & 15, nl = t >> 4;
    float acc = 0.f;
    for (int l0 = 0; l0 < 1024; l0 += 256) {
      __syncthreads();
#pragma unroll
      for (int i = 0; i < 16; ++i) {
        int e = i * 256 + t, l = e >> 4, n = e & 15;
        vs[l][n] = vM[(size_t)(l0 + l) * 16 + n];
        ws[l][n] = Wb[(size_t)(4096 + l0 + l) * 2048 + nbase + n];
      }
      __syncthreads();
#pragma unroll 8
      for (int ll = 0; ll < 256; ++ll)
        acc += vs[ll][m] * ws[ll][nl];
    }
    hVT[(size_t)(nout + nl) * 16 + m] = acc;
  } else if (bid < 4352) {
    // ---- tw1: four 2048x2048 transposes ----
    const int idx = bid - 256;
    const int z = idx >> 10, rem = idx & 1023;
    const float* src = (z == 0 || z == 2) ? W1e : W1r;
    src += (z < 2) ? 0 : (size_t)2048 * 2048;
    bf16* dst = (z < 2) ? W1sT : W1wT;
    dst += (z == 0 || z == 2) ? 0 : (size_t)2048 * 2048;
    transpose64_body(sm, src, dst, 2048, 2048, (rem >> 5) * 64, (rem & 31) * 64, t);
  } else if (bid < 4864) {
    // ---- tw2: W2e [2048,1024] -> W2t ----
    const int idx = bid - 4352;
    transpose64_body(sm, W2e, W2t, LS_, H_, (idx >> 4) * 64, (idx & 15) * 64, t);
  } else if (bid < 8960) {
    // ---- awr ----
    const int idx = bid - 4864;
    const int b = idx >> 4, l0 = (idx & 15) * 64;
    float (*tr)[17] = (float (*)[17])sm;
    float (*ti)[17] = (float (*)[17])(sm + 4352 * 4);
    const float* wrb = wMr + (size_t)b * (LW_ * M_) + (size_t)l0 * 16;
    const float* wib = wMi + (size_t)b * (LW_ * M_) + (size_t)l0 * 16;
#pragma unroll
    for (int i = 0; i < 4; ++i) {
      int e = i * 256 + t, l = e >> 4, m = e & 15;
      tr[l][m] = wrb[e];
      ti[l][m] = wib[e];
    }
    __syncthreads();
    int m = t >> 4, t4 = t & 15;
    bf16* outR = Awr + (size_t)(b * 16 + m) * KW + l0;
#pragma unroll
    for (int j = 0; j < 4; ++j) outR[t4 * 4 + j]        = __float2bfloat16(tr[t4 * 4 + j][m]);
#pragma unroll
    for (int j = 0; j < 4; ++j) outR[1024 + t4 * 4 + j] = __float2bfloat16(ti[t4 * 4 + j][m]);
  } else {
    // ---- sfeat ----
    const int i = (bid - 8960) * 256 + t;
    const int b = i >> 10, l = i & 1023;
    float p = phi[i];
    float s, c;
    sincosf(p, &s, &c);
    sfeat[b * 2048 + l]        = __float2bfloat16(0.03125f * c);
    sfeat[b * 2048 + 1024 + l] = __float2bfloat16(0.03125f * s);
  }
}

// ---------------------------------------------------------------------------
// GEMM_W: 256x256 tile, BK=64, 8 waves (2x4), m201 8-phase schedule (R12).
// R13: hsum absorbed — prologue builds a 16KB LDS table
//   tblHS[bgl][cl] = sum_z hSp[z][bg][c] + bias[c]
// (same summation order as the old hsum kernel -> bit-identical), with an
// explicit VMC(0) so the ring's counted-vmcnt arithmetic stays clean.
// Epilogue reads hs from LDS instead of 32 scattered global loads.
__global__ void __launch_bounds__(512, 2)
gemm1_256_kernel(const bf16* __restrict__ A, const bf16* __restrict__ Bt,
                 const float* __restrict__ hSp, const float* __restrict__ hVT,
                 const float* __restrict__ bias0, const float* __restrict__ bias1,
                 const float* __restrict__ w2r,
                 bf16* __restrict__ outH, float* __restrict__ rhoP) {
  extern __shared__ __align__(16) char smem[];
  constexpr int NKT = KW / 64;   // 32 K-tiles of 64
  constexpr int NI  = NKT / 2;   // 16 iterations (2 tiles each)

  const int tid  = threadIdx.x;
  const int lane = tid & 63;
  const int wave = tid >> 6;
  const int wr = wave >> 2, wc = wave & 3;   // 2 x 4 wave grid, wave-tile 128x64
  const int fr = lane & 15, fq = lane >> 4;
  const int row0 = blockIdx.y * 256, col0 = blockIdx.x * 256;

  float* tblHS = (float*)(smem + 131072);    // [16][256] f32, 16KB

  // ---- hS table prologue (replaces hsum kernel) ----
  {
    const int e0 = tid * 8;                  // 4096 table elems / 512 thr
    const int bgl = e0 >> 8, cl = e0 & 255;
    const int bg = (row0 >> 4) + bgl;
    const int ce = col0 + cl;
    const float* p = hSp + (size_t)bg * N1 + ce;
    f32x4 s0 = *(const f32x4*)p;
    f32x4 s1 = *(const f32x4*)(p + 4);
    s0 = s0 + *(const f32x4*)(p + (size_t)B_ * N1);
    s1 = s1 + *(const f32x4*)(p + (size_t)B_ * N1 + 4);
    s0 = s0 + *(const f32x4*)(p + (size_t)2 * B_ * N1);
    s1 = s1 + *(const f32x4*)(p + (size_t)2 * B_ * N1 + 4);
    s0 = s0 + *(const f32x4*)(p + (size_t)3 * B_ * N1);
    s1 = s1 + *(const f32x4*)(p + (size_t)3 * B_ * N1 + 4);
    const float* bp = (ce < H_) ? &bias0[ce] : &bias1[ce - H_];
    s0 = s0 + *(const f32x4*)bp;
    s1 = s1 + *(const f32x4*)(bp + 4);
    *(f32x4*)&tblHS[e0]     = s0;
    *(f32x4*)&tblHS[e0 + 4] = s1;
  }
  VMC(0);   // table loads fully retired -> ring vmcnt counting stays exact
  SB0();

  // fragment read statics: row = (wr*128 | wc*64) + tile*16 + fr; 128B/row;
  // slot (16B) for k-step ks, octet fq stored at (ks*4+fq)^(fr&7).
  const int xr  = fr & 7;
  const int sK0 = ((fq ^ xr) << 4);
  const int sK1 = (((4 + fq) ^ xr) << 4);
  const int aRowB = (wr * 128 + fr) << 7;
  const int bRowB = 32768 + ((wc * 64 + fr) << 7);

  const char* gA = (const char*)A  + (size_t)row0 * (KW * 2);
  const char* gB = (const char*)Bt + (size_t)col0 * (KW * 2);
  char* buf0 = smem;
  char* buf1 = smem + 65536;

  const int srow  = tid >> 3;
  const int slotU = (tid & 7) ^ (srow & 7);

  auto stageHalf = [&](const char* g, char* ldsOp, int half, int kt) {
#pragma unroll
    for (int r = 0; r < 2; ++r) {
      const int row = half * 128 + r * 64 + srow;
      gld_lds16(g + (size_t)row * (KW * 2) + (size_t)kt * 128 + slotU * 16,
                ldsOp + half * 16384 + r * 8192 + tid * 16);
    }
  };

  f32x4 acc[8][4] = {};

  auto readA4 = [&](const char* buf, int mg, int sk, bf16x8 (&a)[4]) {
    const char* p = buf + aRowB + mg * 8192 + sk;
#pragma unroll
    for (int i = 0; i < 4; ++i) a[i] = *(const bf16x8*)(p + i * 2048);
  };
  auto readB4 = [&](const char* buf, int sk, bf16x8 (&b)[4]) {
    const char* p = buf + bRowB + sk;
#pragma unroll
    for (int n = 0; n < 4; ++n) b[n] = *(const bf16x8*)(p + n * 2048);
  };
  auto mma16 = [&](int mg, bf16x8 (&a)[4], bf16x8 (&b)[4]) {
    __builtin_amdgcn_s_setprio(1);
#pragma unroll
    for (int i = 0; i < 4; ++i)
#pragma unroll
      for (int n = 0; n < 4; ++n)
        acc[mg * 4 + i][n] =
            __builtin_amdgcn_mfma_f32_16x16x32_bf16(a[i], b[n], acc[mg * 4 + i][n], 0, 0, 0);
    __builtin_amdgcn_s_setprio(0);
  };

  // prologue: tile0 -> buf0 (4 halves) + B-lo(1) -> buf1; retire tile0.
  stageHalf(gB, buf0 + 32768, 0, 0);
  stageHalf(gB, buf0 + 32768, 1, 0);
  stageHalf(gA, buf0, 0, 0);
  stageHalf(gA, buf0, 1, 0);
  stageHalf(gB, buf1 + 32768, 0, 1);
  VMC(2);
  BARv();

  for (int t = 0; t < NI; ++t) {
    const int k1 = 2 * t + 1;
    const bool pf = (t + 1 < NI);
    bf16x8 aX[4], aY[4], b0[4], b1[4];

    // P1: buf0 a(m0-3,ks0)+b(ks0); stage B-hi(k1)->buf1
    readA4(buf0, 0, sK0, aX); readB4(buf0, sK0, b0);
    stageHalf(gB, buf1 + 32768, 1, k1);
    BARv(); LGKM(0); SB0();
    mma16(0, aX, b0);
    SB0(); BARv();

    // P2: a(m4-7,ks0); stage A-lo(k1)->buf1
    readA4(buf0, 1, sK0, aY);
    stageHalf(gA, buf1, 0, k1);
    BARv(); LGKM(0); SB0();
    mma16(1, aY, b0);
    SB0(); BARv();

    // P3: a(m0-3,ks1)+b(ks1); stage A-hi(k1)->buf1
    readA4(buf0, 0, sK1, aX); readB4(buf0, sK1, b1);
    stageHalf(gA, buf1, 1, k1);
    BARv(); LGKM(0); SB0();
    mma16(0, aX, b1);
    SB0(); BARv();

    // P4: a(m4-7,ks1); stage B-lo(2t+2)->buf0; VMC(2) guards P5's buf1 reads
    readA4(buf0, 1, sK1, aY);
    if (pf) { stageHalf(gB, buf0 + 32768, 0, 2 * t + 2); VMC(2); }
    else    { VMC(0); }
    BARv(); LGKM(0); SB0();
    mma16(1, aY, b1);
    SB0(); BARv();

    // P5: buf1 a(m0-3,ks0)+b(ks0); stage B-hi(2t+2)->buf0
    readA4(buf1, 0, sK0, aX); readB4(buf1, sK0, b0);
    if (pf) stageHalf(gB, buf0 + 32768, 1, 2 * t + 2);
    BARv(); LGKM(0); SB0();
    mma16(0, aX, b0);
    SB0(); BARv();

    // P6: a(m4-7,ks0); stage A-lo(2t+2)->buf0
    readA4(buf1, 1, sK0, aY);
    if (pf) stageHalf(gA, buf0, 0, 2 * t + 2);
    BARv(); LGKM(0); SB0();
    mma16(1, aY, b0);
    SB0(); BARv();

    // P7: a(m0-3,ks1)+b(ks1); stage A-hi(2t+2)->buf0
    readA4(buf1, 0, sK1, aX); readB4(buf1, sK1, b1);
    if (pf) stageHalf(gA, buf0, 1, 2 * t + 2);
    BARv(); LGKM(0); SB0();
    mma16(0, aX, b1);
    SB0(); BARv();

    // P8: a(m4-7,ks1); stage B-lo(2t+3)->buf1; VMC(2) guards next P1
    readA4(buf1, 1, sK1, aY);
    if (pf) { stageHalf(gB, buf1 + 32768, 0, 2 * t + 3); VMC(2); }
    else    { VMC(0); }
    BARv(); LGKM(0); SB0();
    mma16(1, aY, b1);
    SB0(); BARv();
  }

  if (col0 < H_) {
    // eta half: h = relu(acc + tblHS + hVT)
#pragma unroll
    for (int n = 0; n < 4; ++n) {
      const int c = col0 + wc * 64 + n * 16 + fr;
      const int clo = wc * 64 + n * 16 + fr;
      const f32x4 hv = *(const f32x4*)&hVT[(size_t)c * 16 + fq * 4];
#pragma unroll
      for (int m = 0; m < 8; ++m) {
        const int rbase = row0 + wr * 128 + m * 16;
        const float hs = tblHS[(wr * 8 + m) * 256 + clo];
#pragma unroll
        for (int j = 0; j < 4; ++j) {
          const int r = rbase + fq * 4 + j;
          float v = acc[m][n][j] + hs + hv[j];
          outH[(size_t)r * N1 + c] = __float2bfloat16(v > 0.f ? v : 0.f);
        }
      }
    }
  } else {
    // rho half: partial dot with W2r; no h store
    const int cb = (col0 >> 8) - 8;   // 0..7
    float* rhoT = (float*)smem;       // ring is dead
    f32x4 hv4[4];
    float w2[4];
#pragma unroll
    for (int n = 0; n < 4; ++n) {
      const int c = col0 + wc * 64 + n * 16 + fr;
      hv4[n] = *(const f32x4*)&hVT[(size_t)c * 16 + fq * 4];
      w2[n] = w2r[c - H_];
    }
#pragma unroll
    for (int m = 0; m < 8; ++m) {
      f32x4 rsv = {0.f, 0.f, 0.f, 0.f};
#pragma unroll
      for (int n = 0; n < 4; ++n) {
        const int clo = wc * 64 + n * 16 + fr;
        const float hs = tblHS[(wr * 8 + m) * 256 + clo];
#pragma unroll
        for (int j = 0; j < 4; ++j) {
          float v = acc[m][n][j] + hs + hv4[n][j];
          v = v > 0.f ? v : 0.f;
          rsv[j] += v * w2[n];
        }
      }
#pragma unroll
      for (int j = 0; j < 4; ++j) {
        rsv[j] += __shfl_xor(rsv[j], 1);
        rsv[j] += __shfl_xor(rsv[j], 2);
        rsv[j] += __shfl_xor(rsv[j], 4);
        rsv[j] += __shfl_xor(rsv[j], 8);
      }
      if (fr == 0)
        *(f32x4*)&rhoT[((wr * 4 + wc) << 7) + m * 16 + fq * 4] = rsv;
    }
    __syncthreads();
    if (tid < 256) {
      const int wrr = tid >> 7, lr = tid & 127;
      const float* rt = &rhoT[(wrr * 4) << 7];
      const float s = rt[lr] + rt[128 + lr] + rt[256 + lr] + rt[384 + lr];
      rhoP[(size_t)(row0 + wrr * 128 + lr) * 8 + cb] = s;
    }
  }
}

// ---------------------------------------------------------------------------
// gemm128_pipe (R11-proven): 128x128 tile, BK=32, 4 waves, 4-deep LDS ring,
// tile-ahead reads. EPI 0 (GEMM2): rhoP reduce prologue; out1 scatter;
// out0 = phi - eta. EPI 1 (GEMM_S split-K): blockIdx.z selects K-slice.
template <int EPI, int NT>
__global__ void __launch_bounds__(256, 2)
gemm128_pipe_kernel(const bf16* __restrict__ A, int lda,
                    const bf16* __restrict__ Bt, int ldb,
                    const float* __restrict__ bias0,
                    const float* __restrict__ rhoP, const float* __restrict__ b2r,
                    const float* __restrict__ phi,
                    float* __restrict__ outS, float* __restrict__ out0) {
  extern __shared__ __align__(16) char smem[];

  if (EPI == 1) {
    const int z = blockIdx.z;
    A    += (size_t)z * 512;
    Bt   += (size_t)z * 512;
    outS += (size_t)z * ((size_t)B_ * N1);
  }

  const int tid  = threadIdx.x;
  const int lane = tid & 63;
  const int wave = tid >> 6;                 // 0..3
  const int wr = wave >> 1, wc = wave & 1;   // 2x2 wave grid
  const int fr = lane & 15, fq = lane >> 4;
  const int row0 = blockIdx.y * 128, col0 = blockIdx.x * 128;

  // rho prologue (EPI 0)
  if (EPI == 0) {
    if (tid < 128) {
      const float* pp = &rhoP[(size_t)(row0 + tid) * 8];
      const f32x4 p0 = *(const f32x4*)pp;
      const f32x4 p1 = *(const f32x4*)(pp + 4);
      const float s = p0[0] + p0[1] + p0[2] + p0[3] +
                      p1[0] + p1[1] + p1[2] + p1[3] + b2r[0];
      ((float*)(smem + 65536))[tid] = s;
    }
    LGKM(0);
    SB0();
  }

  const int slotF = (((fr & 1) << 2) | fq) ^ ((fr >> 1) & 7);
  const int aOff = (wr << 12) + ((fr >> 1) << 7) + (slotF << 4);
  const int bOff = 8192 + (wc << 12) + ((fr >> 1) << 7) + (slotF << 4);

  const int lgl = tid >> 3;
  const int su  = (tid & 7) ^ (lgl & 7);
  const int rp0 = lgl * 2 + (su >> 2);
  const int rp1 = (32 + lgl) * 2 + (su >> 2);
  const int kb  = (su & 3) << 4;
  const char* pA0 = (const char*)A  + (size_t)(row0 + rp0) * ((size_t)lda * 2) + kb;
  const char* pA1 = (const char*)A  + (size_t)(row0 + rp1) * ((size_t)lda * 2) + kb;
  const char* pB0 = (const char*)Bt + (size_t)(col0 + rp0) * ((size_t)ldb * 2) + kb;
  const char* pB1 = (const char*)Bt + (size_t)(col0 + rp1) * ((size_t)ldb * 2) + kb;

  auto stageTile = [&](int T) {   // 4 gld per wave
    char* dst = smem + (size_t)(T & 3) * 16384;
    const size_t ko = (size_t)T * 64;
    gld_lds16(pA0 + ko, dst + 0     + tid * 16);
    gld_lds16(pA1 + ko, dst + 4096  + tid * 16);
    gld_lds16(pB0 + ko, dst + 8192  + tid * 16);
    gld_lds16(pB1 + ko, dst + 12288 + tid * 16);
  };

  f32x4 acc[4][4] = {};
  bf16x8 aA[4], aB[4], bA[4], bB[4];

  stageTile(0); stageTile(1); stageTile(2);
  VMC(4);
  __builtin_amdgcn_s_barrier();
  {
    const char* aP0 = smem + aOff;
    const char* bP0 = smem + bOff;
#pragma unroll
    for (int m = 0; m < 4; ++m) aA[m] = *(const bf16x8*)(aP0 + m * 1024);
#pragma unroll
    for (int n = 0; n < 4; ++n) bA[n] = *(const bf16x8*)(bP0 + n * 1024);
  }
  SB0();

  auto doIter = [&](int T, bf16x8 (&aCur)[4], bf16x8 (&bCur)[4],
                    bf16x8 (&aNxt)[4], bf16x8 (&bNxt)[4]) {
    const char* aPn = smem + (size_t)((T + 1) & 3) * 16384 + aOff;
    const char* bPn = smem + (size_t)((T + 1) & 3) * 16384 + bOff;
    const bool rb = (T + 1 < NT);
    const bool pf = (T + 3 < NT);

    if (pf) stageTile(T + 3);
    LGKM(0);                 // aCur,bCur ready (issued during tile T-1)
    SB0();
    if (rb) {
#pragma unroll
      for (int m = 0; m < 4; ++m) aNxt[m] = *(const bf16x8*)(aPn + m * 1024);
#pragma unroll
      for (int n = 0; n < 4; ++n) bNxt[n] = *(const bf16x8*)(bPn + n * 1024);
    }
    SB0();
    __builtin_amdgcn_s_setprio(1);
#pragma unroll
    for (int m = 0; m < 4; ++m)
#pragma unroll
      for (int n = 0; n < 4; ++n)
        acc[m][n] = __builtin_amdgcn_mfma_f32_16x16x32_bf16(aCur[m], bCur[n], acc[m][n], 0, 0, 0);
    __builtin_amdgcn_s_setprio(0);
    SB0();
    if (pf) { VMC(4); }
    else    { VMC(0); }
    __builtin_amdgcn_s_barrier();
  };

  for (int t = 0; t < NT; t += 2) {
    doIter(t,     aA, bA, aB, bB);
    doIter(t + 1, aB, bB, aA, bA);
  }

  if (EPI == 0) {
    const float* rhoL = (const float*)(smem + 65536);
#pragma unroll
    for (int m = 0; m < 4; ++m) {
      const int bg = (row0 >> 4) + wr * 4 + m;                 // batch index
      const f32x4 rv = *(const f32x4*)&rhoL[wr * 64 + m * 16 + fq * 4];
#pragma unroll
      for (int n = 0; n < 4; ++n) {
        const int c = col0 + wc * 64 + n * 16 + fr;
        const float bias = bias0[c];
        float part = 0.f;
#pragma unroll
        for (int j = 0; j < 4; ++j) {
          float v = acc[m][n][j] + bias;
          outS[(size_t)bg * (LS_ * M_) + (size_t)c * M_ + (fq * 4 + j)] = v;
          part += rv[j] * v;
        }
        part += __shfl_xor(part, 16);
        part += __shfl_xor(part, 32);
        if (fq == 0)
          out0[(size_t)bg * LS_ + c] = phi[(size_t)bg * LS_ + c] - part;
      }
    }
  } else {
#pragma unroll
    for (int m = 0; m < 4; ++m) {
#pragma unroll
      for (int n = 0; n < 4; ++n) {
        const int c = col0 + wc * 64 + n * 16 + fr;
#pragma unroll
        for (int j = 0; j < 4; ++j) {
          const int r = row0 + wr * 64 + m * 16 + fq * 4 + j;
          outS[(size_t)r * N1 + c] = acc[m][n][j];
        }
      }
    }
  }
}

// ---------------------------------------------------------------------------
extern "C" void kernel_launch(void* const* d_in, const int* in_sizes, int n_in,
                              void* d_out, int out_size, void* d_ws, size_t ws_size,
                              hipStream_t stream) {
  const float* phi = (const float*)d_in[0];
  const float* wMr = (const float*)d_in[1];
  const float* wMi = (const float*)d_in[2];
  const float* vM  = (const float*)d_in[3];
  const float* W1e = (const float*)d_in[4];
  const float* b1e = (const float*)d_in[5];
  const float* W2e = (const float*)d_in[6];
  const float* b2e = (const float*)d_in[7];
  const float* W1r = (const float*)d_in[8];
  const float* b1r = (const float*)d_in[9];
  const float* W2r = (const float*)d_in[10];
  const float* b2r = (const float*)d_in[11];

  float* out0 = (float*)d_out;            // phi_optimal [B, LS]
  float* out1 = out0 + (size_t)B_ * LS_;  // eta_M^T     [B, LS, M]

  bf16* Awr   = (bf16*)d_ws;                         // [4096, 2048]
  bf16* W1sT  = Awr  + (size_t)ROWS * KW;            // [4096, 2048]
  bf16* W1wT  = W1sT + (size_t)N1 * KW;              // [4096, 2048]
  bf16* h     = W1wT + (size_t)N1 * KW;              // [4096, 4096] (eta half used)
  bf16* W2t   = h + (size_t)ROWS * N1;               // [1024, 2048]
  bf16* sfeat = W2t + (size_t)LS_ * H_;              // [256, 2048]
  float* hSp  = (float*)(sfeat + (size_t)B_ * 2048); // 4 x [256, 4096] partials
  float* hVT  = hSp + (size_t)4 * B_ * N1;           // [4096, 16]
  float* rhoP = hVT + (size_t)N1 * 16;               // [4096, 8] rho partials

  (void)hipFuncSetAttribute(reinterpret_cast<const void*>(gemm1_256_kernel),
                            hipFuncAttributeMaxDynamicSharedMemorySize, 147456);
  (void)hipFuncSetAttribute(reinterpret_cast<const void*>(gemm128_pipe_kernel<0, 64>),
                            hipFuncAttributeMaxDynamicSharedMemorySize, 66048);
  (void)hipFuncSetAttribute(reinterpret_cast<const void*>(gemm128_pipe_kernel<1, 16>),
                            hipFuncAttributeMaxDynamicSharedMemorySize, 65536);

  // merged preprocessing: hv | 4x W1-transpose | W2-transpose | awr | sfeat
  prep_kernel<<<9984, 256, 0, stream>>>(phi, wMr, wMi, vM, W1e, W1r, W2e,
                                        sfeat, Awr, W1sT, W1wT, W2t, hVT);

  // GEMM_S split-K x4: hSp[z] = sfeat @ W1sT[:, z*512:(z+1)*512]^T
  gemm128_pipe_kernel<1, 16><<<dim3(N1 / 128, B_ / 128, 4), 256, 65536, stream>>>(
      sfeat, 2048, W1sT, KW, nullptr, nullptr, nullptr, nullptr, hSp, nullptr);

  // GEMM_W (m201 8-phase + hS-table prologue): h(eta half) = relu(...); rhoP
  gemm1_256_kernel<<<dim3(N1 / 256, ROWS / 256), 512, 147456, stream>>>(
      Awr, W1wT, hSp, hVT, b1e, b1r, W2r, h, rhoP);

  // GEMM2: rho reduce (prologue) + out1 scatter + out0 = phi - eta
  gemm128_pipe_kernel<0, 64><<<dim3(LS_ / 128, ROWS / 128), 256, 66048, stream>>>(
      h, N1, W2t, H_, b2e, rhoP, b2r, phi, out1, out0);
}

// Round 14
// 133.130 us; speedup vs baseline: 1.0836x; 1.0443x over previous
//
#include <hip/hip_runtime.h>
#include <hip/hip_bf16.h>
#include <stdint.h>

// Problem constants
#define B_    256
#define LS_   1024
#define LW_   1024
#define LV_   1024
#define M_    16
#define D_    5120
#define H_    2048
#define ROWS  4096   // B*M
#define N1    4096   // H (eta) + H (rho) fused
#define KW    2048   // K of the per-row (wr|wi) GEMM

typedef __hip_bfloat16 bf16;
typedef __bf16 bf16x8 __attribute__((ext_vector_type(8)));
typedef __bf16 bf16x4 __attribute__((ext_vector_type(4)));
typedef float f32x4 __attribute__((ext_vector_type(4)));

#define SB0() __builtin_amdgcn_sched_barrier(0)
#define LGKM(n) asm volatile("s_waitcnt lgkmcnt(" #n ")" ::: "memory")
#define VMC(n)  asm volatile("s_waitcnt vmcnt(" #n ")" ::: "memory")
#define BARv()  __builtin_amdgcn_s_barrier()

// ---------------------------------------------------------------------------
// async global->LDS, 16B per lane (HW: wave-uniform LDS base + lane*16).
__device__ __forceinline__ void gld_lds16(const void* g, void* l) {
  auto gp = (const __attribute__((address_space(1))) uint32_t*)(uintptr_t)g;
  auto lp = (__attribute__((address_space(3))) uint32_t*)(uint32_t)(uintptr_t)l;
  __builtin_amdgcn_global_load_lds(gp, lp, 16, 0, 0);
}

// ---------------------------------------------------------------------------
// Merged preprocessing kernel (R9-proven): block-range dispatch.
__device__ __forceinline__ void transpose64_body(char* sm, const float* __restrict__ in,
                                                 bf16* __restrict__ out,
                                                 int C, int R, int r0, int c0, int t) {
  float (*tile)[65] = (float (*)[65])sm;
  const int tx = t & 15, ty = t >> 4;   // 16 x 16
#pragma unroll
  for (int i = 0; i < 4; ++i) {
    const float4 v = *(const float4*)&in[(size_t)(r0 + ty + i * 16) * C + c0 + tx * 4];
    tile[ty + i * 16][tx * 4 + 0] = v.x;
    tile[ty + i * 16][tx * 4 + 1] = v.y;
    tile[ty + i * 16][tx * 4 + 2] = v.z;
    tile[ty + i * 16][tx * 4 + 3] = v.w;
  }
  __syncthreads();
#pragma unroll
  for (int i = 0; i < 4; ++i) {
    const int n = c0 + ty + i * 16;
    bf16x4 o;
#pragma unroll
    for (int j = 0; j < 4; ++j) o[j] = (__bf16)tile[tx * 4 + j][ty + i * 16];
    *(bf16x4*)&out[(size_t)n * R + r0 + tx * 4] = o;
  }
}

__global__ void __launch_bounds__(256)
prep_kernel(const float* __restrict__ phi,
            const float* __restrict__ wMr, const float* __restrict__ wMi,
            const float* __restrict__ vM,
            const float* __restrict__ W1e, const float* __restrict__ W1r,
            const float* __restrict__ W2e,
            bf16* __restrict__ sfeat, bf16* __restrict__ Awr,
            bf16* __restrict__ W1sT, bf16* __restrict__ W1wT,
            bf16* __restrict__ W2t, float* __restrict__ hVT) {
  __shared__ __align__(16) char sm[32768];
  const int bid = blockIdx.x;
  const int t = threadIdx.x;

  if (bid < 256) {
    // ---- hv ----
    float (*vs)[16] = (float (*)[16])sm;
    float (*ws)[16] = (float (*)[16])(sm + 16384);
    const float* Wb = (bid < 128) ? W1e : W1r;
    const int nbase = (bid & 127) * 16;
    const int nout = ((bid < 128) ? 0 : 2048) + nbase;
    const int m = t & 15, nl = t >> 4;
    float acc = 0.f;
    for (int l0 = 0; l0 < 1024; l0 += 256) {
      __syncthreads();
#pragma unroll
      for (int i = 0; i < 16; ++i) {
        int e = i * 256 + t, l = e >> 4, n = e & 15;
        vs[l][n] = vM[(size_t)(l0 + l) * 16 + n];
        ws[l][n] = Wb[(size_t)(4096 + l0 + l) * 2048 + nbase + n];
      }
      __syncthreads();
#pragma unroll 8
      for (int ll = 0; ll < 256; ++ll)
        acc += vs[ll][m] * ws[ll][nl];
    }
    hVT[(size_t)(nout + nl) * 16 + m] = acc;
  } else if (bid < 4352) {
    // ---- tw1: four 2048x2048 transposes ----
    const int idx = bid - 256;
    const int z = idx >> 10, rem = idx & 1023;
    const float* src = (z == 0 || z == 2) ? W1e : W1r;
    src += (z < 2) ? 0 : (size_t)2048 * 2048;
    bf16* dst = (z < 2) ? W1sT : W1wT;
    dst += (z == 0 || z == 2) ? 0 : (size_t)2048 * 2048;
    transpose64_body(sm, src, dst, 2048, 2048, (rem >> 5) * 64, (rem & 31) * 64, t);
  } else if (bid < 4864) {
    // ---- tw2: W2e [2048,1024] -> W2t ----
    const int idx = bid - 4352;
    transpose64_body(sm, W2e, W2t, LS_, H_, (idx >> 4) * 64, (idx & 15) * 64, t);
  } else if (bid < 8960) {
    // ---- awr ----
    const int idx = bid - 4864;
    const int b = idx >> 4, l0 = (idx & 15) * 64;
    float (*tr)[17] = (float (*)[17])sm;
    float (*ti)[17] = (float (*)[17])(sm + 4352 * 4);
    const float* wrb = wMr + (size_t)b * (LW_ * M_) + (size_t)l0 * 16;
    const float* wib = wMi + (size_t)b * (LW_ * M_) + (size_t)l0 * 16;
#pragma unroll
    for (int i = 0; i < 4; ++i) {
      int e = i * 256 + t, l = e >> 4, m = e & 15;
      tr[l][m] = wrb[e];
      ti[l][m] = wib[e];
    }
    __syncthreads();
    int m = t >> 4, t4 = t & 15;
    bf16* outR = Awr + (size_t)(b * 16 + m) * KW + l0;
#pragma unroll
    for (int j = 0; j < 4; ++j) outR[t4 * 4 + j]        = __float2bfloat16(tr[t4 * 4 + j][m]);
#pragma unroll
    for (int j = 0; j < 4; ++j) outR[1024 + t4 * 4 + j] = __float2bfloat16(ti[t4 * 4 + j][m]);
  } else {
    // ---- sfeat ----
    const int i = (bid - 8960) * 256 + t;
    const int b = i >> 10, l = i & 1023;
    float p = phi[i];
    float s, c;
    sincosf(p, &s, &c);
    sfeat[b * 2048 + l]        = __float2bfloat16(0.03125f * c);
    sfeat[b * 2048 + 1024 + l] = __float2bfloat16(0.03125f * s);
  }
}

// ---------------------------------------------------------------------------
// GEMM_W: 256x256 tile, BK=64, 8 waves (2x4), m201 8-phase schedule (R12) +
// hS-table prologue (R13). Epilogue: eta half -> relu store; rho half ->
// W2r partial dots (R10).
__global__ void __launch_bounds__(512, 2)
gemm1_256_kernel(const bf16* __restrict__ A, const bf16* __restrict__ Bt,
                 const float* __restrict__ hSp, const float* __restrict__ hVT,
                 const float* __restrict__ bias0, const float* __restrict__ bias1,
                 const float* __restrict__ w2r,
                 bf16* __restrict__ outH, float* __restrict__ rhoP) {
  extern __shared__ __align__(16) char smem[];
  constexpr int NKT = KW / 64;   // 32 K-tiles of 64
  constexpr int NI  = NKT / 2;   // 16 iterations (2 tiles each)

  const int tid  = threadIdx.x;
  const int lane = tid & 63;
  const int wave = tid >> 6;
  const int wr = wave >> 2, wc = wave & 3;   // 2 x 4 wave grid, wave-tile 128x64
  const int fr = lane & 15, fq = lane >> 4;
  const int row0 = blockIdx.y * 256, col0 = blockIdx.x * 256;

  float* tblHS = (float*)(smem + 131072);    // [16][256] f32, 16KB

  // ---- hS table prologue (bit-identical to old hsum) ----
  {
    const int e0 = tid * 8;
    const int bgl = e0 >> 8, cl = e0 & 255;
    const int bg = (row0 >> 4) + bgl;
    const int ce = col0 + cl;
    const float* p = hSp + (size_t)bg * N1 + ce;
    f32x4 s0 = *(const f32x4*)p;
    f32x4 s1 = *(const f32x4*)(p + 4);
    s0 = s0 + *(const f32x4*)(p + (size_t)B_ * N1);
    s1 = s1 + *(const f32x4*)(p + (size_t)B_ * N1 + 4);
    s0 = s0 + *(const f32x4*)(p + (size_t)2 * B_ * N1);
    s1 = s1 + *(const f32x4*)(p + (size_t)2 * B_ * N1 + 4);
    s0 = s0 + *(const f32x4*)(p + (size_t)3 * B_ * N1);
    s1 = s1 + *(const f32x4*)(p + (size_t)3 * B_ * N1 + 4);
    const float* bp = (ce < H_) ? &bias0[ce] : &bias1[ce - H_];
    s0 = s0 + *(const f32x4*)bp;
    s1 = s1 + *(const f32x4*)(bp + 4);
    *(f32x4*)&tblHS[e0]     = s0;
    *(f32x4*)&tblHS[e0 + 4] = s1;
  }
  VMC(0);
  SB0();

  const int xr  = fr & 7;
  const int sK0 = ((fq ^ xr) << 4);
  const int sK1 = (((4 + fq) ^ xr) << 4);
  const int aRowB = (wr * 128 + fr) << 7;
  const int bRowB = 32768 + ((wc * 64 + fr) << 7);

  const char* gA = (const char*)A  + (size_t)row0 * (KW * 2);
  const char* gB = (const char*)Bt + (size_t)col0 * (KW * 2);
  char* buf0 = smem;
  char* buf1 = smem + 65536;

  const int srow  = tid >> 3;
  const int slotU = (tid & 7) ^ (srow & 7);

  auto stageHalf = [&](const char* g, char* ldsOp, int half, int kt) {
#pragma unroll
    for (int r = 0; r < 2; ++r) {
      const int row = half * 128 + r * 64 + srow;
      gld_lds16(g + (size_t)row * (KW * 2) + (size_t)kt * 128 + slotU * 16,
                ldsOp + half * 16384 + r * 8192 + tid * 16);
    }
  };

  f32x4 acc[8][4] = {};

  auto readA4 = [&](const char* buf, int mg, int sk, bf16x8 (&a)[4]) {
    const char* p = buf + aRowB + mg * 8192 + sk;
#pragma unroll
    for (int i = 0; i < 4; ++i) a[i] = *(const bf16x8*)(p + i * 2048);
  };
  auto readB4 = [&](const char* buf, int sk, bf16x8 (&b)[4]) {
    const char* p = buf + bRowB + sk;
#pragma unroll
    for (int n = 0; n < 4; ++n) b[n] = *(const bf16x8*)(p + n * 2048);
  };
  auto mma16 = [&](int mg, bf16x8 (&a)[4], bf16x8 (&b)[4]) {
    __builtin_amdgcn_s_setprio(1);
#pragma unroll
    for (int i = 0; i < 4; ++i)
#pragma unroll
      for (int n = 0; n < 4; ++n)
        acc[mg * 4 + i][n] =
            __builtin_amdgcn_mfma_f32_16x16x32_bf16(a[i], b[n], acc[mg * 4 + i][n], 0, 0, 0);
    __builtin_amdgcn_s_setprio(0);
  };

  // prologue: tile0 -> buf0 (4 halves) + B-lo(1) -> buf1; retire tile0.
  stageHalf(gB, buf0 + 32768, 0, 0);
  stageHalf(gB, buf0 + 32768, 1, 0);
  stageHalf(gA, buf0, 0, 0);
  stageHalf(gA, buf0, 1, 0);
  stageHalf(gB, buf1 + 32768, 0, 1);
  VMC(2);
  BARv();

  for (int t = 0; t < NI; ++t) {
    const int k1 = 2 * t + 1;
    const bool pf = (t + 1 < NI);
    bf16x8 aX[4], aY[4], b0[4], b1[4];

    // P1
    readA4(buf0, 0, sK0, aX); readB4(buf0, sK0, b0);
    stageHalf(gB, buf1 + 32768, 1, k1);
    BARv(); LGKM(0); SB0();
    mma16(0, aX, b0);
    SB0(); BARv();

    // P2
    readA4(buf0, 1, sK0, aY);
    stageHalf(gA, buf1, 0, k1);
    BARv(); LGKM(0); SB0();
    mma16(1, aY, b0);
    SB0(); BARv();

    // P3
    readA4(buf0, 0, sK1, aX); readB4(buf0, sK1, b1);
    stageHalf(gA, buf1, 1, k1);
    BARv(); LGKM(0); SB0();
    mma16(0, aX, b1);
    SB0(); BARv();

    // P4
    readA4(buf0, 1, sK1, aY);
    if (pf) { stageHalf(gB, buf0 + 32768, 0, 2 * t + 2); VMC(2); }
    else    { VMC(0); }
    BARv(); LGKM(0); SB0();
    mma16(1, aY, b1);
    SB0(); BARv();

    // P5
    readA4(buf1, 0, sK0, aX); readB4(buf1, sK0, b0);
    if (pf) stageHalf(gB, buf0 + 32768, 1, 2 * t + 2);
    BARv(); LGKM(0); SB0();
    mma16(0, aX, b0);
    SB0(); BARv();

    // P6
    readA4(buf1, 1, sK0, aY);
    if (pf) stageHalf(gA, buf0, 0, 2 * t + 2);
    BARv(); LGKM(0); SB0();
    mma16(1, aY, b0);
    SB0(); BARv();

    // P7
    readA4(buf1, 0, sK1, aX); readB4(buf1, sK1, b1);
    if (pf) stageHalf(gA, buf0, 1, 2 * t + 2);
    BARv(); LGKM(0); SB0();
    mma16(0, aX, b1);
    SB0(); BARv();

    // P8
    readA4(buf1, 1, sK1, aY);
    if (pf) { stageHalf(gB, buf1 + 32768, 0, 2 * t + 3); VMC(2); }
    else    { VMC(0); }
    BARv(); LGKM(0); SB0();
    mma16(1, aY, b1);
    SB0(); BARv();
  }

  if (col0 < H_) {
#pragma unroll
    for (int n = 0; n < 4; ++n) {
      const int c = col0 + wc * 64 + n * 16 + fr;
      const int clo = wc * 64 + n * 16 + fr;
      const f32x4 hv = *(const f32x4*)&hVT[(size_t)c * 16 + fq * 4];
#pragma unroll
      for (int m = 0; m < 8; ++m) {
        const int rbase = row0 + wr * 128 + m * 16;
        const float hs = tblHS[(wr * 8 + m) * 256 + clo];
#pragma unroll
        for (int j = 0; j < 4; ++j) {
          const int r = rbase + fq * 4 + j;
          float v = acc[m][n][j] + hs + hv[j];
          outH[(size_t)r * N1 + c] = __float2bfloat16(v > 0.f ? v : 0.f);
        }
      }
    }
  } else {
    const int cb = (col0 >> 8) - 8;   // 0..7
    float* rhoT = (float*)smem;
    f32x4 hv4[4];
    float w2[4];
#pragma unroll
    for (int n = 0; n < 4; ++n) {
      const int c = col0 + wc * 64 + n * 16 + fr;
      hv4[n] = *(const f32x4*)&hVT[(size_t)c * 16 + fq * 4];
      w2[n] = w2r[c - H_];
    }
#pragma unroll
    for (int m = 0; m < 8; ++m) {
      f32x4 rsv = {0.f, 0.f, 0.f, 0.f};
#pragma unroll
      for (int n = 0; n < 4; ++n) {
        const int clo = wc * 64 + n * 16 + fr;
        const float hs = tblHS[(wr * 8 + m) * 256 + clo];
#pragma unroll
        for (int j = 0; j < 4; ++j) {
          float v = acc[m][n][j] + hs + hv4[n][j];
          v = v > 0.f ? v : 0.f;
          rsv[j] += v * w2[n];
        }
      }
#pragma unroll
      for (int j = 0; j < 4; ++j) {
        rsv[j] += __shfl_xor(rsv[j], 1);
        rsv[j] += __shfl_xor(rsv[j], 2);
        rsv[j] += __shfl_xor(rsv[j], 4);
        rsv[j] += __shfl_xor(rsv[j], 8);
      }
      if (fr == 0)
        *(f32x4*)&rhoT[((wr * 4 + wc) << 7) + m * 16 + fq * 4] = rsv;
    }
    __syncthreads();
    if (tid < 256) {
      const int wrr = tid >> 7, lr = tid & 127;
      const float* rt = &rhoT[(wrr * 4) << 7];
      const float s = rt[lr] + rt[128 + lr] + rt[256 + lr] + rt[384 + lr];
      rhoP[(size_t)(row0 + wrr * 128 + lr) * 8 + cb] = s;
    }
  }
}

// ---------------------------------------------------------------------------
// GEMM2 (R14): 128x128 tile, 8 waves with intra-block split-K. Waves kh=w>>2
// handle K-tiles 2i+kh into separate accumulators (same 64x64 wave-tile per
// w&3); 6-deep 16KB ring (96KB); 2 tiles staged/iter (2 glds/thread each);
// VMC(4)/iter. End: kh=1 acc -> LDS (XOR-swizzled), kh=0 adds + epilogue
// (rhoL prologue table at 96KB; out1 scatter; out0 = phi - eta).
__global__ void __launch_bounds__(512, 2)
gemm2_8w_kernel(const bf16* __restrict__ A, int lda,
                const bf16* __restrict__ Bt, int ldb,
                const float* __restrict__ bias0,
                const float* __restrict__ rhoP, const float* __restrict__ b2r,
                const float* __restrict__ phi,
                float* __restrict__ outS, float* __restrict__ out0) {
  extern __shared__ __align__(16) char smem[];
  constexpr int NT = 64;   // K = 2048, BK = 32

  const int tid  = threadIdx.x;
  const int lane = tid & 63;
  const int wave = tid >> 6;                 // 0..7
  const int kh = wave >> 2;                  // K-half
  const int w2 = wave & 3;
  const int wr = w2 >> 1, wc = w2 & 1;       // 2x2 within half
  const int fr = lane & 15, fq = lane >> 4;
  const int row0 = blockIdx.y * 128, col0 = blockIdx.x * 128;

  float* rhoL = (float*)(smem + 98304);      // [128] f32

  // rho prologue (waves 0,1 = kh0)
  if (tid < 128) {
    const float* pp = &rhoP[(size_t)(row0 + tid) * 8];
    const f32x4 p0 = *(const f32x4*)pp;
    const f32x4 p1 = *(const f32x4*)(pp + 4);
    rhoL[tid] = p0[0] + p0[1] + p0[2] + p0[3] +
                p1[0] + p1[1] + p1[2] + p1[3] + b2r[0];
  }
  VMC(0); LGKM(0);
  SB0();

  // fragment read statics (same algebra as gemm128)
  const int slotF = (((fr & 1) << 2) | fq) ^ ((fr >> 1) & 7);
  const int aOff = (wr << 12) + ((fr >> 1) << 7) + (slotF << 4);
  const int bOff = 8192 + (wc << 12) + ((fr >> 1) << 7) + (slotF << 4);

  // staging statics: 512 threads, thread t covers LDS line t>>3, slot t&7 of
  // each operand region; source (row, kByte) from the inverse swizzle.
  const int sline = tid >> 3;
  const int sls   = tid & 7;
  const int ssu   = sls ^ (sline & 7);
  const int srowi = (sline >> 3) * 16 + (sline & 7) * 2 + (ssu >> 2);  // 0..127
  const int skb   = (ssu & 3) << 4;
  const char* pAg = (const char*)A  + (size_t)(row0 + srowi) * ((size_t)lda * 2) + skb;
  const char* pBg = (const char*)Bt + (size_t)(col0 + srowi) * ((size_t)ldb * 2) + skb;

  auto stageTile = [&](int T, int slot) {   // 2 glds per thread
    char* dst = smem + (size_t)slot * 16384;
    const size_t ko = (size_t)T * 64;
    gld_lds16(pAg + ko, dst + tid * 16);
    gld_lds16(pBg + ko, dst + 8192 + tid * 16);
  };

  f32x4 acc[4][4] = {};

  // prologue: stage tiles 0..3 into slots 0..3; retire 0,1 (keep 2,3 flying)
  stageTile(0, 0); stageTile(1, 1); stageTile(2, 2); stageTile(3, 3);
  VMC(4);
  BARv();

  int s0 = 0;   // slot of tile 2i (cycles 0,2,4)
  for (int i = 0; i < 32; ++i) {
    const char* buf = smem + (size_t)(s0 + kh) * 16384;
    const char* aP = buf + aOff;
    const char* bP = buf + bOff;
    bf16x8 a[4], b[4];
#pragma unroll
    for (int m = 0; m < 4; ++m) a[m] = *(const bf16x8*)(aP + m * 1024);
#pragma unroll
    for (int n = 0; n < 4; ++n) b[n] = *(const bf16x8*)(bP + n * 1024);
    SB0();
    if (i < 30) {
      const int sA = (s0 >= 2) ? s0 - 2 : 4;   // (2i+4) % 6
      stageTile(2 * i + 4, sA);
      stageTile(2 * i + 5, (sA + 1 == 6) ? 0 : sA + 1);
    }
    SB0();
    LGKM(0);
    SB0();
    __builtin_amdgcn_s_setprio(1);
#pragma unroll
    for (int m = 0; m < 4; ++m)
#pragma unroll
      for (int n = 0; n < 4; ++n)
        acc[m][n] = __builtin_amdgcn_mfma_f32_16x16x32_bf16(a[m], b[n], acc[m][n], 0, 0, 0);
    __builtin_amdgcn_s_setprio(0);
    SB0();
    if (i < 30) { VMC(4); }
    else        { VMC(0); }
    BARv();
    s0 = (s0 == 4) ? 0 : s0 + 2;
  }

  // ---- split-K reduce: kh=1 -> LDS (XOR-swizzled slots), kh=0 adds ----
  if (kh == 1) {
    char* base = smem + (((w2 << 6) + lane) << 8);
#pragma unroll
    for (int m = 0; m < 4; ++m)
#pragma unroll
      for (int n = 0; n < 4; ++n) {
        const int idx = (m * 4 + n) ^ (lane & 15);
        *(f32x4*)(base + idx * 16) = acc[m][n];
      }
  }
  LGKM(0);
  BARv();
  if (kh == 0) {
    const char* base = smem + (((w2 << 6) + lane) << 8);
#pragma unroll
    for (int m = 0; m < 4; ++m)
#pragma unroll
      for (int n = 0; n < 4; ++n) {
        const int idx = (m * 4 + n) ^ (lane & 15);
        acc[m][n] = acc[m][n] + *(const f32x4*)(base + idx * 16);
      }

    // epilogue (kh=0 waves only)
#pragma unroll
    for (int m = 0; m < 4; ++m) {
      const int bg = (row0 >> 4) + wr * 4 + m;                 // batch index
      const f32x4 rv = *(const f32x4*)&rhoL[wr * 64 + m * 16 + fq * 4];
#pragma unroll
      for (int n = 0; n < 4; ++n) {
        const int c = col0 + wc * 64 + n * 16 + fr;
        const float bias = bias0[c];
        float part = 0.f;
#pragma unroll
        for (int j = 0; j < 4; ++j) {
          float v = acc[m][n][j] + bias;
          outS[(size_t)bg * (LS_ * M_) + (size_t)c * M_ + (fq * 4 + j)] = v;
          part += rv[j] * v;
        }
        part += __shfl_xor(part, 16);
        part += __shfl_xor(part, 32);
        if (fq == 0)
          out0[(size_t)bg * LS_ + c] = phi[(size_t)bg * LS_ + c] - part;
      }
    }
  }
}

// ---------------------------------------------------------------------------
// gemm128_pipe (R11-proven, EPI=1 only): GEMM_S split-K x4.
template <int NT>
__global__ void __launch_bounds__(256, 2)
gemmS_pipe_kernel(const bf16* __restrict__ A, int lda,
                  const bf16* __restrict__ Bt, int ldb,
                  float* __restrict__ outS) {
  extern __shared__ __align__(16) char smem[];

  const int z = blockIdx.z;
  A    += (size_t)z * 512;
  Bt   += (size_t)z * 512;
  outS += (size_t)z * ((size_t)B_ * N1);

  const int tid  = threadIdx.x;
  const int lane = tid & 63;
  const int wave = tid >> 6;
  const int wr = wave >> 1, wc = wave & 1;
  const int fr = lane & 15, fq = lane >> 4;
  const int row0 = blockIdx.y * 128, col0 = blockIdx.x * 128;

  const int slotF = (((fr & 1) << 2) | fq) ^ ((fr >> 1) & 7);
  const int aOff = (wr << 12) + ((fr >> 1) << 7) + (slotF << 4);
  const int bOff = 8192 + (wc << 12) + ((fr >> 1) << 7) + (slotF << 4);

  const int lgl = tid >> 3;
  const int su  = (tid & 7) ^ (lgl & 7);
  const int rp0 = lgl * 2 + (su >> 2);
  const int rp1 = (32 + lgl) * 2 + (su >> 2);
  const int kb  = (su & 3) << 4;
  const char* pA0 = (const char*)A  + (size_t)(row0 + rp0) * ((size_t)lda * 2) + kb;
  const char* pA1 = (const char*)A  + (size_t)(row0 + rp1) * ((size_t)lda * 2) + kb;
  const char* pB0 = (const char*)Bt + (size_t)(col0 + rp0) * ((size_t)ldb * 2) + kb;
  const char* pB1 = (const char*)Bt + (size_t)(col0 + rp1) * ((size_t)ldb * 2) + kb;

  auto stageTile = [&](int T) {
    char* dst = smem + (size_t)(T & 3) * 16384;
    const size_t ko = (size_t)T * 64;
    gld_lds16(pA0 + ko, dst + 0     + tid * 16);
    gld_lds16(pA1 + ko, dst + 4096  + tid * 16);
    gld_lds16(pB0 + ko, dst + 8192  + tid * 16);
    gld_lds16(pB1 + ko, dst + 12288 + tid * 16);
  };

  f32x4 acc[4][4] = {};
  bf16x8 aA[4], aB[4], bA[4], bB[4];

  stageTile(0); stageTile(1); stageTile(2);
  VMC(4);
  __builtin_amdgcn_s_barrier();
  {
    const char* aP0 = smem + aOff;
    const char* bP0 = smem + bOff;
#pragma unroll
    for (int m = 0; m < 4; ++m) aA[m] = *(const bf16x8*)(aP0 + m * 1024);
#pragma unroll
    for (int n = 0; n < 4; ++n) bA[n] = *(const bf16x8*)(bP0 + n * 1024);
  }
  SB0();

  auto doIter = [&](int T, bf16x8 (&aCur)[4], bf16x8 (&bCur)[4],
                    bf16x8 (&aNxt)[4], bf16x8 (&bNxt)[4]) {
    const char* aPn = smem + (size_t)((T + 1) & 3) * 16384 + aOff;
    const char* bPn = smem + (size_t)((T + 1) & 3) * 16384 + bOff;
    const bool rb = (T + 1 < NT);
    const bool pf = (T + 3 < NT);

    if (pf) stageTile(T + 3);
    LGKM(0);
    SB0();
    if (rb) {
#pragma unroll
      for (int m = 0; m < 4; ++m) aNxt[m] = *(const bf16x8*)(aPn + m * 1024);
#pragma unroll
      for (int n = 0; n < 4; ++n) bNxt[n] = *(const bf16x8*)(bPn + n * 1024);
    }
    SB0();
    __builtin_amdgcn_s_setprio(1);
#pragma unroll
    for (int m = 0; m < 4; ++m)
#pragma unroll
      for (int n = 0; n < 4; ++n)
        acc[m][n] = __builtin_amdgcn_mfma_f32_16x16x32_bf16(aCur[m], bCur[n], acc[m][n], 0, 0, 0);
    __builtin_amdgcn_s_setprio(0);
    SB0();
    if (pf) { VMC(4); }
    else    { VMC(0); }
    __builtin_amdgcn_s_barrier();
  };

  for (int t = 0; t < NT; t += 2) {
    doIter(t,     aA, bA, aB, bB);
    doIter(t + 1, aB, bB, aA, bA);
  }

#pragma unroll
  for (int m = 0; m < 4; ++m) {
#pragma unroll
    for (int n = 0; n < 4; ++n) {
      const int c = col0 + wc * 64 + n * 16 + fr;
#pragma unroll
      for (int j = 0; j < 4; ++j) {
        const int r = row0 + wr * 64 + m * 16 + fq * 4 + j;
        outS[(size_t)r * N1 + c] = acc[m][n][j];
      }
    }
  }
}

// ---------------------------------------------------------------------------
extern "C" void kernel_launch(void* const* d_in, const int* in_sizes, int n_in,
                              void* d_out, int out_size, void* d_ws, size_t ws_size,
                              hipStream_t stream) {
  const float* phi = (const float*)d_in[0];
  const float* wMr = (const float*)d_in[1];
  const float* wMi = (const float*)d_in[2];
  const float* vM  = (const float*)d_in[3];
  const float* W1e = (const float*)d_in[4];
  const float* b1e = (const float*)d_in[5];
  const float* W2e = (const float*)d_in[6];
  const float* b2e = (const float*)d_in[7];
  const float* W1r = (const float*)d_in[8];
  const float* b1r = (const float*)d_in[9];
  const float* W2r = (const float*)d_in[10];
  const float* b2r = (const float*)d_in[11];

  float* out0 = (float*)d_out;            // phi_optimal [B, LS]
  float* out1 = out0 + (size_t)B_ * LS_;  // eta_M^T     [B, LS, M]

  bf16* Awr   = (bf16*)d_ws;                         // [4096, 2048]
  bf16* W1sT  = Awr  + (size_t)ROWS * KW;            // [4096, 2048]
  bf16* W1wT  = W1sT + (size_t)N1 * KW;              // [4096, 2048]
  bf16* h     = W1wT + (size_t)N1 * KW;              // [4096, 4096] (eta half used)
  bf16* W2t   = h + (size_t)ROWS * N1;               // [1024, 2048]
  bf16* sfeat = W2t + (size_t)LS_ * H_;              // [256, 2048]
  float* hSp  = (float*)(sfeat + (size_t)B_ * 2048); // 4 x [256, 4096] partials
  float* hVT  = hSp + (size_t)4 * B_ * N1;           // [4096, 16]
  float* rhoP = hVT + (size_t)N1 * 16;               // [4096, 8] rho partials

  (void)hipFuncSetAttribute(reinterpret_cast<const void*>(gemm1_256_kernel),
                            hipFuncAttributeMaxDynamicSharedMemorySize, 147456);
  (void)hipFuncSetAttribute(reinterpret_cast<const void*>(gemm2_8w_kernel),
                            hipFuncAttributeMaxDynamicSharedMemorySize, 98816);
  (void)hipFuncSetAttribute(reinterpret_cast<const void*>(gemmS_pipe_kernel<16>),
                            hipFuncAttributeMaxDynamicSharedMemorySize, 65536);

  // merged preprocessing: hv | 4x W1-transpose | W2-transpose | awr | sfeat
  prep_kernel<<<9984, 256, 0, stream>>>(phi, wMr, wMi, vM, W1e, W1r, W2e,
                                        sfeat, Awr, W1sT, W1wT, W2t, hVT);

  // GEMM_S split-K x4: hSp[z] = sfeat @ W1sT[:, z*512:(z+1)*512]^T
  gemmS_pipe_kernel<16><<<dim3(N1 / 128, B_ / 128, 4), 256, 65536, stream>>>(
      sfeat, 2048, W1sT, KW, hSp);

  // GEMM_W (m201 8-phase + hS-table prologue): h(eta half) = relu(...); rhoP
  gemm1_256_kernel<<<dim3(N1 / 256, ROWS / 256), 512, 147456, stream>>>(
      Awr, W1wT, hSp, hVT, b1e, b1r, W2r, h, rhoP);

  // GEMM2 (8-wave split-K): rho reduce + out1 scatter + out0 = phi - eta
  gemm2_8w_kernel<<<dim3(LS_ / 128, ROWS / 128), 512, 98816, stream>>>(
      h, N1, W2t, H_, b2e, rhoP, b2r, phi, out1, out0);
}